// Round 2
// baseline (7318.851 us; speedup 1.0000x reference)
//
#include <hip/hip_runtime.h>

// ---------------- problem constants ----------------
#define B_   2
#define T_   4096
#define D_   2048
#define HV_  32
#define AK_  128
#define UV_  128
#define KD_  2048          // KEY_DIM
#define VD_  4096          // VALUE_DIM
#define CD_  8192          // CONV_DIM
#define CHK  64            // chunk size
#define NCH  (T_/CHK)      // 64 chunks
#define USL  32            // U-slice per core block

typedef __attribute__((ext_vector_type(4))) float  f32x4;
typedef __attribute__((ext_vector_type(8))) short  short8;
typedef __attribute__((ext_vector_type(4))) short  short4b;
typedef __attribute__((ext_vector_type(8))) unsigned short u16x8;

__device__ __forceinline__ float bf2f(unsigned short u) {
  return __uint_as_float(((unsigned)u) << 16);
}
__device__ __forceinline__ unsigned short f2bf(float f) { // RNE
  unsigned u = __float_as_uint(f);
  return (unsigned short)((u + 0x7fffu + ((u >> 16) & 1u)) >> 16);
}

// ---------------- transpose f32 (K,N) -> bf16 (N,K) ----------------
__global__ __launch_bounds__(256) void k_transpose(const float* __restrict__ src,
                                                   unsigned short* __restrict__ dst,
                                                   int K, int N) {
  __shared__ float tile[32][33];
  int k0 = blockIdx.x * 32, n0 = blockIdx.y * 32;
  int tx = threadIdx.x, ty = threadIdx.y;
  #pragma unroll
  for (int i = 0; i < 32; i += 8)
    tile[ty + i][tx] = src[(size_t)(k0 + ty + i) * N + n0 + tx];
  __syncthreads();
  #pragma unroll
  for (int i = 0; i < 32; i += 8)
    dst[(size_t)(n0 + ty + i) * K + k0 + tx] = f2bf(tile[tx][ty + i]);
}

// ---------------- MFMA GEMM: C(M,N) = A(M,K) * BT(N,K)^T ----------------
// A is f32 (converted to bf16 during LDS staging) when AF32, else bf16.
__device__ __forceinline__ void storeC(float* p, float v) { *p = v; }
__device__ __forceinline__ void storeC(unsigned short* p, float v) { *p = f2bf(v); }

template <bool AF32, typename CT>
__global__ __launch_bounds__(256) void k_gemm(const void* __restrict__ Av,
                                              const unsigned short* __restrict__ BT,
                                              CT* __restrict__ C, int M, int N, int K) {
  __shared__ short As[128 * 32];
  __shared__ short Bs[128 * 32];
  const int tid  = threadIdx.x;
  const size_t bm = (size_t)blockIdx.x * 128;
  const size_t bn = (size_t)blockIdx.y * 128;
  const int lane = tid & 63;
  const int wave = tid >> 6;
  const int wm = (wave >> 1) * 64;
  const int wn = (wave & 1) * 64;
  const int fr = lane & 15;
  const int kg = lane >> 4;
  const short* Bg = (const short*)BT + bn * K;

  f32x4 acc[4][4];
  #pragma unroll
  for (int i = 0; i < 4; ++i)
    #pragma unroll
    for (int j2 = 0; j2 < 4; ++j2) acc[i][j2] = (f32x4){0.f, 0.f, 0.f, 0.f};

  for (int kt = 0; kt < K; kt += 32) {
    __syncthreads();
    if constexpr (AF32) {
      const float* Ag = (const float*)Av + bm * (size_t)K;
      #pragma unroll
      for (int s = 0; s < 4; ++s) {           // 1024 float4-chunks (128x32 f32)
        int ch = s * 256 + tid;
        int r = ch >> 3, c4 = (ch & 7) * 4;
        float4 v = *(const float4*)(Ag + (size_t)r * K + kt + c4);
        short4b sv = { (short)f2bf(v.x), (short)f2bf(v.y), (short)f2bf(v.z), (short)f2bf(v.w) };
        *(short4b*)&As[r * 32 + c4] = sv;
      }
    } else {
      const short* Ag = (const short*)Av + bm * (size_t)K;
      #pragma unroll
      for (int s = 0; s < 2; ++s) {           // 512 16B-chunks
        int ch = s * 256 + tid;
        int r = ch >> 2, kc8 = (ch & 3) * 8;
        *(short8*)&As[ch * 8] = *(const short8*)(Ag + (size_t)r * K + kt + kc8);
      }
    }
    #pragma unroll
    for (int s = 0; s < 2; ++s) {
      int ch = s * 256 + tid;
      int r = ch >> 2, kc8 = (ch & 3) * 8;
      *(short8*)&Bs[ch * 8] = *(const short8*)(Bg + (size_t)r * K + kt + kc8);
    }
    __syncthreads();
    short8 af[4], bfr[4];
    #pragma unroll
    for (int mi = 0; mi < 4; ++mi) af[mi]  = *(const short8*)&As[(wm + mi*16 + fr)*32 + kg*8];
    #pragma unroll
    for (int ni = 0; ni < 4; ++ni) bfr[ni] = *(const short8*)&Bs[(wn + ni*16 + fr)*32 + kg*8];
    #pragma unroll
    for (int mi = 0; mi < 4; ++mi)
      #pragma unroll
      for (int ni = 0; ni < 4; ++ni)
        acc[mi][ni] = __builtin_amdgcn_mfma_f32_16x16x32_bf16(af[mi], bfr[ni], acc[mi][ni], 0, 0, 0);
  }
  // C/D layout: col = lane&15, row = (lane>>4)*4 + e
  #pragma unroll
  for (int mi = 0; mi < 4; ++mi)
    #pragma unroll
    for (int ni = 0; ni < 4; ++ni) {
      size_t row = bm + wm + mi * 16 + kg * 4;
      size_t col = bn + wn + ni * 16 + fr;
      #pragma unroll
      for (int e = 0; e < 4; ++e) storeC(&C[(row + e) * (size_t)N + col], acc[mi][ni][e]);
    }
}

// ---------------- beta / g from hidden (f32, exact) ----------------
__global__ __launch_bounds__(256) void k_beta_g(const float* __restrict__ hidden,
                                                const float* __restrict__ Wb,
                                                const float* __restrict__ Wa,
                                                const float* __restrict__ dt_bias,
                                                const float* __restrict__ A_log,
                                                float* __restrict__ betab,
                                                float* __restrict__ gbuf) {
  const int tid = threadIdx.x;
  const int r = tid >> 5, hh = tid & 31;
  const size_t bt = (size_t)blockIdx.x * 8 + r;
  const float* hrow = hidden + bt * D_;
  float sb = 0.f, sa = 0.f;
  for (int d = 0; d < D_; ++d) {
    float hv = hrow[d];
    sb += hv * Wb[d * 32 + hh];
    sa += hv * Wa[d * 32 + hh];
  }
  float beta = 1.f / (1.f + expf(-sb));
  float xg = sa + dt_bias[hh];
  float sp = (xg > 20.f) ? xg : log1pf(expf(xg));
  float g = -expf(A_log[hh]) * sp;
  int b = (int)(bt >> 12);
  int t = (int)(bt & (T_ - 1));
  size_t o = ((size_t)b * HV_ + hh) * T_ + t;
  betab[o] = beta;
  gbuf[o] = g;
}

// ---------------- gated delta rule core (conv+silu+l2norm fused) ----------------
// grid: 256 blocks = (b, h, u-slice); block 256 threads.
__global__ __launch_bounds__(256) void k_core(const unsigned short* __restrict__ mixed,
                                              const float* __restrict__ cw,
                                              const float* __restrict__ gbuf,
                                              const float* __restrict__ betab,
                                              unsigned short* __restrict__ xout) {
  __shared__ float S[128][36];       // state
  __shared__ float kc[CHK][132];     // k rows (post conv/silu/l2norm)
  __shared__ float qc[CHK][132];     // q rows (post conv/silu/l2norm, *A^-0.5)
  __shared__ float P[CHK][68];       // L, then T-I, then intra
  __shared__ float W1[CHK][68];      // L^(2^k) power buffer
  __shared__ float vbs[CHK][36];     // v*beta, then R, then qS
  __shared__ float vns[CHK][36];     // v_corr, then v_new
  __shared__ float gj[CHK], eg[CHK], bet[CHK], edec[CHK];
  __shared__ float wcv[288][4];      // conv weights: [0,128)=q, [128,256)=k, [256,288)=v

  const int tid = threadIdx.x;
  const int blk = blockIdx.x;
  const int ug = blk & 3;
  const int h  = (blk >> 2) & 31;
  const int b  = blk >> 7;
  const int hk = h >> 1;             // GQA
  const int u0 = ug * USL;
  const int wv = tid >> 6;
  const int ty = tid >> 4, tx = tid & 15;
  const int ch0q = hk * AK_;
  const int ch0k = KD_ + hk * AK_;
  const int ch0v = 2 * KD_ + h * UV_ + u0;

  for (int i = tid; i < 128 * 36; i += 256) (&S[0][0])[i] = 0.f;
  for (int i = tid; i < 288; i += 256) {
    int gc = (i < 128) ? (ch0q + i) : ((i < 256) ? (ch0k + (i - 128)) : (ch0v + (i - 256)));
    *(f32x4*)&wcv[i][0] = *(const f32x4*)&cw[(size_t)gc * 4];
  }
  const float* gsrc = gbuf  + ((size_t)b * HV_ + h) * T_;
  const float* bsrc = betab + ((size_t)b * HV_ + h) * T_;
  __syncthreads();

  for (int j = 0; j < NCH; ++j) {
    const int t0 = j * CHK;
    if (tid < CHK) { gj[tid] = gsrc[t0 + tid]; bet[tid] = bsrc[t0 + tid]; }
    __syncthreads();
    if (tid == 0) { float run = 0.f; for (int l = 0; l < CHK; ++l) { run += gj[l]; gj[l] = run; } }

    // ---- fused conv(K=4)+silu loads: q/k (64x128) ----
    #pragma unroll
    for (int it = 0; it < 4; ++it) {
      int i = it * 256 + tid;
      int l = i >> 4, a8 = (i & 15) * 8;
      int tg = t0 + l;
      float aq[8] = {0,0,0,0,0,0,0,0}, ak[8] = {0,0,0,0,0,0,0,0};
      #pragma unroll
      for (int p = 0; p < 4; ++p) {
        int ts = tg - 3 + p;
        if (ts >= 0) {
          size_t rb = ((size_t)b * T_ + ts) * CD_;
          u16x8 qv = *(const u16x8*)&mixed[rb + ch0q + a8];
          u16x8 kv = *(const u16x8*)&mixed[rb + ch0k + a8];
          #pragma unroll
          for (int e = 0; e < 8; ++e) {
            aq[e] += bf2f(qv[e]) * wcv[a8 + e][p];
            ak[e] += bf2f(kv[e]) * wcv[128 + a8 + e][p];
          }
        }
      }
      #pragma unroll
      for (int e = 0; e < 8; ++e) {
        float xq = aq[e], xk = ak[e];
        qc[l][a8 + e] = xq / (1.f + expf(-xq));
        kc[l][a8 + e] = xk / (1.f + expf(-xk));
      }
    }
    // ---- fused conv+silu v-slice (64x32), * beta ----
    {
      int l = tid >> 2, u8 = (tid & 3) * 8;
      int tg = t0 + l;
      float av[8] = {0,0,0,0,0,0,0,0};
      #pragma unroll
      for (int p = 0; p < 4; ++p) {
        int ts = tg - 3 + p;
        if (ts >= 0) {
          size_t rb = ((size_t)b * T_ + ts) * CD_;
          u16x8 vv = *(const u16x8*)&mixed[rb + ch0v + u8];
          #pragma unroll
          for (int e = 0; e < 8; ++e) av[e] += bf2f(vv[e]) * wcv[256 + u8 + e][p];
        }
      }
      float be = bet[l];
      #pragma unroll
      for (int e = 0; e < 8; ++e) { float x = av[e]; vbs[l][u8 + e] = (x / (1.f + expf(-x))) * be; }
    }
    __syncthreads();

    // ---- eg/edec + l2norm(q,k) (4 threads/row) ----
    if (tid < CHK) { float gl = gj[CHK - 1]; eg[tid] = expf(gj[tid]); edec[tid] = expf(gl - gj[tid]); }
    {
      int r = tid >> 2, c0 = (tid & 3) * 32;
      float sq = 0.f, sk = 0.f;
      for (int c = 0; c < 32; c += 4) {
        f32x4 qv = *(const f32x4*)&qc[r][c0 + c];
        f32x4 kv = *(const f32x4*)&kc[r][c0 + c];
        sq += qv.x * qv.x + qv.y * qv.y + qv.z * qv.z + qv.w * qv.w;
        sk += kv.x * kv.x + kv.y * kv.y + kv.z * kv.z + kv.w * kv.w;
      }
      sq += __shfl_xor(sq, 1); sq += __shfl_xor(sq, 2);
      sk += __shfl_xor(sk, 1); sk += __shfl_xor(sk, 2);
      float scq = rsqrtf(sq + 1e-6f) * 0.08838834764831845f;  // * 128^-0.5
      float sck = rsqrtf(sk + 1e-6f);
      for (int c = 0; c < 32; c += 4) {
        f32x4 qv = *(const f32x4*)&qc[r][c0 + c];
        f32x4 kv = *(const f32x4*)&kc[r][c0 + c];
        qv *= scq; kv *= sck;
        *(f32x4*)&qc[r][c0 + c] = qv;
        *(f32x4*)&kc[r][c0 + c] = kv;
      }
    }
    __syncthreads();

    // ---- phase 1: L[l][m] = -(beta_l * (k_l . k_m)) * exp(gj_l - gj_m), l>m ----
    {
      float r4[4][4] = {};
      for (int a4 = 0; a4 < AK_; a4 += 4) {
        float4 kl[4], km[4];
        #pragma unroll
        for (int i = 0; i < 4; ++i) kl[i] = *(const float4*)&kc[ty * 4 + i][a4];
        #pragma unroll
        for (int jj = 0; jj < 4; ++jj) km[jj] = *(const float4*)&kc[tx * 4 + jj][a4];
        #pragma unroll
        for (int i = 0; i < 4; ++i)
          #pragma unroll
          for (int jj = 0; jj < 4; ++jj)
            r4[i][jj] += kl[i].x * km[jj].x + kl[i].y * km[jj].y + kl[i].z * km[jj].z + kl[i].w * km[jj].w;
      }
      #pragma unroll
      for (int i = 0; i < 4; ++i)
        #pragma unroll
        for (int jj = 0; jj < 4; ++jj) {
          int l = ty * 4 + i, m = tx * 4 + jj;
          P[l][m] = (l > m) ? (-bet[l] * r4[i][jj] * expf(gj[l] - gj[m])) : 0.f;
        }
    }
    __syncthreads();

    // ---- phase 2: T - I = (I+L)(I+L^2)...(I+L^32) - I  via doubling ----
    for (int i = tid; i < CHK * CHK; i += 256) { int l = i >> 6, m = i & 63; W1[l][m] = P[l][m]; }
    __syncthreads();
    #pragma unroll
    for (int dk = 1; dk <= 5; ++dk) {
      const int p2 = 1 << (dk - 1);
      float s4[4][4] = {};
      {
        const int hi = 16 * wv + 15 - p2;      // wave-uniform sparsity bound
        for (int jm = p2; jm <= hi; ++jm) {
          float wl[4];
          #pragma unroll
          for (int i = 0; i < 4; ++i) wl[i] = W1[ty * 4 + i][jm];
          float4 wr = *(const float4*)&W1[jm][tx * 4];
          #pragma unroll
          for (int i = 0; i < 4; ++i) {
            s4[i][0] += wl[i] * wr.x; s4[i][1] += wl[i] * wr.y;
            s4[i][2] += wl[i] * wr.z; s4[i][3] += wl[i] * wr.w;
          }
        }
      }
      __syncthreads();
      #pragma unroll
      for (int i = 0; i < 4; ++i) {
        float4 t4 = {s4[i][0], s4[i][1], s4[i][2], s4[i][3]};
        *(float4*)&W1[ty * 4 + i][tx * 4] = t4;   // W1 = L^(2^dk)
      }
      __syncthreads();
      float pu[4][4];
      #pragma unroll
      for (int i = 0; i < 4; ++i) {
        float4 pv = *(const float4*)&P[ty * 4 + i][tx * 4];
        float4 wv4 = *(const float4*)&W1[ty * 4 + i][tx * 4];
        pu[i][0] = pv.x + wv4.x; pu[i][1] = pv.y + wv4.y;
        pu[i][2] = pv.z + wv4.z; pu[i][3] = pv.w + wv4.w;
      }
      {
        const int lo = p2 << 1, hi = 16 * wv + 14;
        for (int jm = lo; jm <= hi; ++jm) {
          float pl[4];
          #pragma unroll
          for (int i = 0; i < 4; ++i) pl[i] = P[ty * 4 + i][jm];
          float4 wr = *(const float4*)&W1[jm][tx * 4];
          #pragma unroll
          for (int i = 0; i < 4; ++i) {
            pu[i][0] += pl[i] * wr.x; pu[i][1] += pl[i] * wr.y;
            pu[i][2] += pl[i] * wr.z; pu[i][3] += pl[i] * wr.w;
          }
        }
      }
      __syncthreads();
      #pragma unroll
      for (int i = 0; i < 4; ++i) {
        float4 t4 = {pu[i][0], pu[i][1], pu[i][2], pu[i][3]};
        *(float4*)&P[ty * 4 + i][tx * 4] = t4;
      }
      __syncthreads();
    }

    // ---- phase 3: v_corr = (I+P) @ vb  -> vns ----
    #pragma unroll
    for (int s = 0; s < 2; ++s) {
      int slot = s * 256 + tid;
      int l = slot >> 3, u4 = (slot & 7) * 4;
      float4 acc = *(const float4*)&vbs[l][u4];
      const int hi = 32 * s + 8 * wv + 6;
      for (int jm = 0; jm <= hi; ++jm) {
        float pv = P[l][jm];
        float4 vv = *(const float4*)&vbs[jm][u4];
        acc.x += pv * vv.x; acc.y += pv * vv.y; acc.z += pv * vv.z; acc.w += pv * vv.w;
      }
      *(float4*)&vns[l][u4] = acc;
    }
    __syncthreads();

    // ---- phase 4: R[j] = beta_j * e^{gj_j} * (k_j . S)  -> vbs (overwrite) ----
    #pragma unroll
    for (int s = 0; s < 2; ++s) {
      int slot = s * 256 + tid;
      int l = slot >> 3, u4 = (slot & 7) * 4;
      float4 acc = {0.f, 0.f, 0.f, 0.f};
      for (int a = 0; a < 128; ++a) {
        float kv = kc[l][a];
        float4 sv = *(const float4*)&S[a][u4];
        acc.x += kv * sv.x; acc.y += kv * sv.y; acc.z += kv * sv.z; acc.w += kv * sv.w;
      }
      float sc = bet[l] * eg[l];
      acc.x *= sc; acc.y *= sc; acc.z *= sc; acc.w *= sc;
      *(float4*)&vbs[l][u4] = acc;
    }
    __syncthreads();

    // ---- phase 5: v_new = v_corr - (I+P) @ R ----
    #pragma unroll
    for (int s = 0; s < 2; ++s) {
      int slot = s * 256 + tid;
      int l = slot >> 3, u4 = (slot & 7) * 4;
      float4 acc = *(const float4*)&vbs[l][u4];
      const int hi = 32 * s + 8 * wv + 6;
      for (int jm = 0; jm <= hi; ++jm) {
        float pv = P[l][jm];
        float4 rv = *(const float4*)&vbs[jm][u4];
        acc.x += pv * rv.x; acc.y += pv * rv.y; acc.z += pv * rv.z; acc.w += pv * rv.w;
      }
      float4 cur = *(const float4*)&vns[l][u4];
      cur.x -= acc.x; cur.y -= acc.y; cur.z -= acc.z; cur.w -= acc.w;
      *(float4*)&vns[l][u4] = cur;
    }
    __syncthreads();

    // ---- phase 6: intra = (q . k) * exp(gj_l - gj_m), l>=m  -> P (reuse) ----
    {
      float r4[4][4] = {};
      for (int a4 = 0; a4 < AK_; a4 += 4) {
        float4 ql[4], km[4];
        #pragma unroll
        for (int i = 0; i < 4; ++i) ql[i] = *(const float4*)&qc[ty * 4 + i][a4];
        #pragma unroll
        for (int jj = 0; jj < 4; ++jj) km[jj] = *(const float4*)&kc[tx * 4 + jj][a4];
        #pragma unroll
        for (int i = 0; i < 4; ++i)
          #pragma unroll
          for (int jj = 0; jj < 4; ++jj)
            r4[i][jj] += ql[i].x * km[jj].x + ql[i].y * km[jj].y + ql[i].z * km[jj].z + ql[i].w * km[jj].w;
      }
      #pragma unroll
      for (int i = 0; i < 4; ++i)
        #pragma unroll
        for (int jj = 0; jj < 4; ++jj) {
          int l = ty * 4 + i, m = tx * 4 + jj;
          P[l][m] = (l >= m) ? (r4[i][jj] * expf(gj[l] - gj[m])) : 0.f;
        }
    }
    // ---- phase 7: qS = q @ S -> vbs (reuse; before S update) ----
    #pragma unroll
    for (int s = 0; s < 2; ++s) {
      int slot = s * 256 + tid;
      int l = slot >> 3, u4 = (slot & 7) * 4;
      float4 acc = {0.f, 0.f, 0.f, 0.f};
      for (int a = 0; a < 128; ++a) {
        float qv = qc[l][a];
        float4 sv = *(const float4*)&S[a][u4];
        acc.x += qv * sv.x; acc.y += qv * sv.y; acc.z += qv * sv.z; acc.w += qv * sv.w;
      }
      *(float4*)&vbs[l][u4] = acc;
    }
    __syncthreads();

    // ---- phase 8: out = e^{gj} * qS + intra @ v_new  -> global ----
    #pragma unroll
    for (int s = 0; s < 2; ++s) {
      int slot = s * 256 + tid;
      int l = slot >> 3, u4 = (slot & 7) * 4;
      float4 acc = *(const float4*)&vbs[l][u4];
      float el = eg[l];
      acc.x *= el; acc.y *= el; acc.z *= el; acc.w *= el;
      const int hi = 32 * s + 8 * wv + 7;
      for (int m = 0; m <= hi; ++m) {
        float pv = P[l][m];
        float4 vv = *(const float4*)&vns[m][u4];
        acc.x += pv * vv.x; acc.y += pv * vv.y; acc.z += pv * vv.z; acc.w += pv * vv.w;
      }
      size_t o = (((size_t)b * T_ + t0 + l) * HV_ + h) * UV_ + u0 + u4;
      unsigned p0 = (unsigned)f2bf(acc.x) | ((unsigned)f2bf(acc.y) << 16);
      unsigned p1 = (unsigned)f2bf(acc.z) | ((unsigned)f2bf(acc.w) << 16);
      *(uint2*)&xout[o] = make_uint2(p0, p1);
    }
    // ---- phase 9: S = S * e^{g_last} + sum_l k_l * e^{g_last-gj_l} * v_new_l ----
    {
      float egl = eg[CHK - 1];
      #pragma unroll
      for (int s = 0; s < 4; ++s) {
        int slot = s * 256 + tid;
        int a = slot >> 3, u4 = (slot & 7) * 4;
        float4 sv = *(const float4*)&S[a][u4];
        sv.x *= egl; sv.y *= egl; sv.z *= egl; sv.w *= egl;
        for (int l = 0; l < CHK; ++l) {
          float kv = kc[l][a] * edec[l];
          float4 vv = *(const float4*)&vns[l][u4];
          sv.x += kv * vv.x; sv.y += kv * vv.y; sv.z += kv * vv.z; sv.w += kv * vv.w;
        }
        *(float4*)&S[a][u4] = sv;
      }
    }
    __syncthreads();
  }
}

// ---------------- x * silu(z) -> RMSNorm -> bf16 ----------------
__global__ __launch_bounds__(256) void k_gate_norm(const unsigned short* __restrict__ x,
                                                   const unsigned short* __restrict__ z,
                                                   const float* __restrict__ nw,
                                                   unsigned short* __restrict__ out) {
  const int row = blockIdx.x * 4 + (threadIdx.x >> 6);
  const int lane = threadIdx.x & 63;
  const unsigned short* xp = x + (size_t)row * UV_;
  const unsigned short* zp = z + (size_t)row * UV_;
  float x0 = bf2f(xp[lane]), x1 = bf2f(xp[lane + 64]);
  float z0 = bf2f(zp[lane]), z1 = bf2f(zp[lane + 64]);
  float g0 = x0 * (z0 / (1.f + expf(-z0)));
  float g1 = x1 * (z1 / (1.f + expf(-z1)));
  float s = g0 * g0 + g1 * g1;
  #pragma unroll
  for (int off = 32; off > 0; off >>= 1) s += __shfl_xor(s, off);
  float r = rsqrtf(s * (1.f / UV_) + 1e-6f);
  out[(size_t)row * UV_ + lane]      = f2bf(nw[lane] * g0 * r);
  out[(size_t)row * UV_ + lane + 64] = f2bf(nw[lane + 64] * g1 * r);
}

// ---------------- launcher ----------------
extern "C" void kernel_launch(void* const* d_in, const int* in_sizes, int n_in,
                              void* d_out, int out_size, void* d_ws, size_t ws_size,
                              hipStream_t stream) {
  (void)in_sizes; (void)n_in; (void)out_size; (void)ws_size;
  const float* hidden  = (const float*)d_in[0];
  const float* W_qkv   = (const float*)d_in[1];
  const float* W_z     = (const float*)d_in[2];
  const float* W_b     = (const float*)d_in[3];
  const float* W_a     = (const float*)d_in[4];
  const float* conv_w  = (const float*)d_in[5];
  const float* dt_bias = (const float*)d_in[6];
  const float* A_log   = (const float*)d_in[7];
  const float* norm_w  = (const float*)d_in[8];
  const float* W_out   = (const float*)d_in[9];
  float* out = (float*)d_out;

  // workspace layout — 226 MiB total, heavy region reuse (lifetimes disjoint):
  //  [  0, 128) MiB mixedraw (G1 out -> core);  after core: zb [0,64) + wzT [64,80) + woutT [80,96)
  //  [ 96, 160) MiB normed (gate_norm out) — overlays mixed tail (dead) + wqkvT (dead)
  //  [128, 160) MiB wqkvT (setup -> G1, dead before normed is written)
  //  [160, 162) MiB betab, gbuf
  //  [162, 226) MiB xcore (core out -> gate_norm)
  const size_t MB = 1048576ull;
  char* w = (char*)d_ws;
  unsigned short* mixedraw = (unsigned short*)(w);
  unsigned short* zb       = (unsigned short*)(w);
  unsigned short* wzT      = (unsigned short*)(w + 64 * MB);
  unsigned short* woutT    = (unsigned short*)(w + 80 * MB);
  unsigned short* normed   = (unsigned short*)(w + 96 * MB);
  unsigned short* wqkvT    = (unsigned short*)(w + 128 * MB);
  float*          betab    = (float*)(w + 160 * MB);
  float*          gbuf     = (float*)(w + 161 * MB);
  unsigned short* xcore    = (unsigned short*)(w + 162 * MB);

  // 1. W_qkv^T
  k_transpose<<<dim3(D_ / 32, CD_ / 32), dim3(32, 8), 0, stream>>>(W_qkv, wqkvT, D_, CD_);
  // 2. mixed = hidden @ W_qkv   (A read as f32)
  k_gemm<true, unsigned short><<<dim3(64, 64), 256, 0, stream>>>(hidden, wqkvT, mixedraw, 8192, 8192, 2048);
  // 3. beta/g
  k_beta_g<<<dim3(B_ * T_ / 8), 256, 0, stream>>>(hidden, W_b, W_a, dt_bias, A_log, betab, gbuf);
  // 4. core (fused conv+silu+l2norm)
  k_core<<<dim3(256), 256, 0, stream>>>(mixedraw, conv_w, gbuf, betab, xcore);
  // 5. W_z^T into dead mixed region
  k_transpose<<<dim3(D_ / 32, VD_ / 32), dim3(32, 8), 0, stream>>>(W_z, wzT, D_, VD_);
  // 6. z = hidden @ W_z into dead mixed region
  k_gemm<true, unsigned short><<<dim3(64, 32), 256, 0, stream>>>(hidden, wzT, zb, 8192, 4096, 2048);
  // 7. W_out^T into dead mixed region
  k_transpose<<<dim3(VD_ / 32, D_ / 32), dim3(32, 8), 0, stream>>>(W_out, woutT, VD_, D_);
  // 8. gate + RMSNorm
  k_gate_norm<<<dim3(B_ * T_ * HV_ / 4), 256, 0, stream>>>(xcore, zb, norm_w, normed);
  // 9. out = normed @ W_out
  k_gemm<false, float><<<dim3(64, 16), 256, 0, stream>>>(normed, woutT, out, 8192, 2048, 4096);
}

// Round 3
// 2151.229 us; speedup vs baseline: 3.4022x; 3.4022x over previous
//
#include <hip/hip_runtime.h>

// ---------------- problem constants ----------------
#define B_   2
#define T_   4096
#define D_   2048
#define HV_  32
#define AK_  128
#define UV_  128
#define KD_  2048          // KEY_DIM
#define VD_  4096          // VALUE_DIM
#define CD_  8192          // CONV_DIM
#define CHK  64            // chunk size
#define NCH  (T_/CHK)      // 64 chunks

typedef __attribute__((ext_vector_type(4))) float  f32x4;
typedef __attribute__((ext_vector_type(8))) short  short8;
typedef __attribute__((ext_vector_type(4))) short  short4b;
typedef __attribute__((ext_vector_type(8))) unsigned short u16x8;
typedef __attribute__((ext_vector_type(4))) unsigned short u16x4;

__device__ __forceinline__ float bf2f(unsigned short u) {
  return __uint_as_float(((unsigned)u) << 16);
}
__device__ __forceinline__ unsigned short f2bf(float f) { // RNE
  unsigned u = __float_as_uint(f);
  return (unsigned short)((u + 0x7fffu + ((u >> 16) & 1u)) >> 16);
}

// ---------------- transpose f32 (K,N) -> bf16 (N,K) ----------------
__global__ __launch_bounds__(256) void k_transpose(const float* __restrict__ src,
                                                   unsigned short* __restrict__ dst,
                                                   int K, int N) {
  __shared__ float tile[32][33];
  int k0 = blockIdx.x * 32, n0 = blockIdx.y * 32;
  int tx = threadIdx.x, ty = threadIdx.y;
  #pragma unroll
  for (int i = 0; i < 32; i += 8)
    tile[ty + i][tx] = src[(size_t)(k0 + ty + i) * N + n0 + tx];
  __syncthreads();
  #pragma unroll
  for (int i = 0; i < 32; i += 8)
    dst[(size_t)(n0 + ty + i) * K + k0 + tx] = f2bf(tile[tx][ty + i]);
}

// ---------------- MFMA GEMM: C(M,N) = A(M,K) * BT(N,K)^T ----------------
__device__ __forceinline__ void storeC(float* p, float v) { *p = v; }
__device__ __forceinline__ void storeC(unsigned short* p, float v) { *p = f2bf(v); }

template <bool AF32, typename CT>
__global__ __launch_bounds__(256) void k_gemm(const void* __restrict__ Av,
                                              const unsigned short* __restrict__ BT,
                                              CT* __restrict__ C, int M, int N, int K) {
  __shared__ short As[128 * 32];
  __shared__ short Bs[128 * 32];
  const int tid  = threadIdx.x;
  const size_t bm = (size_t)blockIdx.x * 128;
  const size_t bn = (size_t)blockIdx.y * 128;
  const int lane = tid & 63;
  const int wave = tid >> 6;
  const int wm = (wave >> 1) * 64;
  const int wn = (wave & 1) * 64;
  const int fr = lane & 15;
  const int kg = lane >> 4;
  const short* Bg = (const short*)BT + bn * K;

  f32x4 acc[4][4];
  #pragma unroll
  for (int i = 0; i < 4; ++i)
    #pragma unroll
    for (int j2 = 0; j2 < 4; ++j2) acc[i][j2] = (f32x4){0.f, 0.f, 0.f, 0.f};

  for (int kt = 0; kt < K; kt += 32) {
    __syncthreads();
    if constexpr (AF32) {
      const float* Ag = (const float*)Av + bm * (size_t)K;
      #pragma unroll
      for (int s = 0; s < 4; ++s) {
        int ch = s * 256 + tid;
        int r = ch >> 3, c4 = (ch & 7) * 4;
        float4 v = *(const float4*)(Ag + (size_t)r * K + kt + c4);
        short4b sv = { (short)f2bf(v.x), (short)f2bf(v.y), (short)f2bf(v.z), (short)f2bf(v.w) };
        *(short4b*)&As[r * 32 + c4] = sv;
      }
    } else {
      const short* Ag = (const short*)Av + bm * (size_t)K;
      #pragma unroll
      for (int s = 0; s < 2; ++s) {
        int ch = s * 256 + tid;
        int r = ch >> 2, kc8 = (ch & 3) * 8;
        *(short8*)&As[ch * 8] = *(const short8*)(Ag + (size_t)r * K + kt + kc8);
      }
    }
    #pragma unroll
    for (int s = 0; s < 2; ++s) {
      int ch = s * 256 + tid;
      int r = ch >> 2, kc8 = (ch & 3) * 8;
      *(short8*)&Bs[ch * 8] = *(const short8*)(Bg + (size_t)r * K + kt + kc8);
    }
    __syncthreads();
    short8 af[4], bfr[4];
    #pragma unroll
    for (int mi = 0; mi < 4; ++mi) af[mi]  = *(const short8*)&As[(wm + mi*16 + fr)*32 + kg*8];
    #pragma unroll
    for (int ni = 0; ni < 4; ++ni) bfr[ni] = *(const short8*)&Bs[(wn + ni*16 + fr)*32 + kg*8];
    #pragma unroll
    for (int mi = 0; mi < 4; ++mi)
      #pragma unroll
      for (int ni = 0; ni < 4; ++ni)
        acc[mi][ni] = __builtin_amdgcn_mfma_f32_16x16x32_bf16(af[mi], bfr[ni], acc[mi][ni], 0, 0, 0);
  }
  #pragma unroll
  for (int mi = 0; mi < 4; ++mi)
    #pragma unroll
    for (int ni = 0; ni < 4; ++ni) {
      size_t row = bm + wm + mi * 16 + kg * 4;
      size_t col = bn + wn + ni * 16 + fr;
      #pragma unroll
      for (int e = 0; e < 4; ++e) storeC(&C[(row + e) * (size_t)N + col], acc[mi][ni][e]);
    }
}

// ---------------- beta / g from hidden (f32, exact) ----------------
__global__ __launch_bounds__(256) void k_beta_g(const float* __restrict__ hidden,
                                                const float* __restrict__ Wb,
                                                const float* __restrict__ Wa,
                                                const float* __restrict__ dt_bias,
                                                const float* __restrict__ A_log,
                                                float* __restrict__ betab,
                                                float* __restrict__ gbuf) {
  const int tid = threadIdx.x;
  const int r = tid >> 5, hh = tid & 31;
  const size_t bt = (size_t)blockIdx.x * 8 + r;
  const float* hrow = hidden + bt * D_;
  float sb = 0.f, sa = 0.f;
  for (int d = 0; d < D_; ++d) {
    float hv = hrow[d];
    sb += hv * Wb[d * 32 + hh];
    sa += hv * Wa[d * 32 + hh];
  }
  float beta = 1.f / (1.f + expf(-sb));
  float xg = sa + dt_bias[hh];
  float sp = (xg > 20.f) ? xg : log1pf(expf(xg));
  float g = -expf(A_log[hh]) * sp;
  int b = (int)(bt >> 12);
  int t = (int)(bt & (T_ - 1));
  size_t o = ((size_t)b * HV_ + hh) * T_ + t;
  betab[o] = beta;
  gbuf[o] = g;
}

// ---------------- conv + silu + l2norm for q,k -> qn,kn (b,hk,t,128) bf16 ----------------
__global__ __launch_bounds__(256) void k_qkv(const unsigned short* __restrict__ mqk,
                                             const float* __restrict__ cw,
                                             unsigned short* __restrict__ qn,
                                             unsigned short* __restrict__ kn) {
  const int row = blockIdx.x;          // b*T + t
  const int b = row >> 12, t = row & (T_ - 1);
  const int tid = threadIdx.x;
  const int c0 = tid * 16;
  float4 w[16];
  #pragma unroll
  for (int e = 0; e < 16; ++e) w[e] = *(const float4*)&cw[(size_t)(c0 + e) * 4];
  float acc[16];
  #pragma unroll
  for (int e = 0; e < 16; ++e) acc[e] = 0.f;
  #pragma unroll
  for (int p = 0; p < 4; ++p) {
    int ts = t - 3 + p;
    if (ts < 0) continue;
    const unsigned short* src = mqk + (size_t)(b * T_ + ts) * 4096 + c0;
    u16x8 v0 = *(const u16x8*)src;
    u16x8 v1 = *(const u16x8*)(src + 8);
    #pragma unroll
    for (int e = 0; e < 8; ++e) {
      acc[e]     += bf2f(v0[e]) * ((const float*)&w[e])[p];
      acc[8 + e] += bf2f(v1[e]) * ((const float*)&w[8 + e])[p];
    }
  }
  float s = 0.f;
  #pragma unroll
  for (int e = 0; e < 16; ++e) {
    float x = acc[e];
    x = x / (1.f + expf(-x));
    acc[e] = x;
    s += x * x;
  }
  s += __shfl_xor(s, 1); s += __shfl_xor(s, 2); s += __shfl_xor(s, 4);
  float sc = rsqrtf(s + 1e-6f);
  bool isq = (c0 < KD_);
  if (isq) sc *= 0.08838834764831845f;   // * 128^-0.5 for q
  int ch = isq ? c0 : (c0 - KD_);
  int hk = ch >> 7, cc = ch & 127;
  unsigned short* dst = (isq ? qn : kn) + ((size_t)(b * 16 + hk) * T_ + t) * 128 + cc;
  u16x8 o0, o1;
  #pragma unroll
  for (int e = 0; e < 8; ++e) { o0[e] = f2bf(acc[e] * sc); o1[e] = f2bf(acc[8 + e] * sc); }
  *(u16x8*)dst = o0;
  *(u16x8*)(dst + 8) = o1;
}

// ---------------- prep: per (b,h,j) compute T = (I-L)^{-1} bf16 + gj cumsum ----------------
__global__ __launch_bounds__(256) void k_prep(const unsigned short* __restrict__ kn,
                                              const float* __restrict__ gbuf,
                                              const float* __restrict__ betab,
                                              unsigned short* __restrict__ Tg,
                                              float* __restrict__ gjc) {
  __shared__ unsigned short kl[CHK][136];
  __shared__ float L[CHK][65];
  __shared__ float W1[CHK][65];
  __shared__ float gj[CHK], bet[CHK];
  const int tid = threadIdx.x;
  const int blk = blockIdx.x;
  const int j = blk & 63, h = (blk >> 6) & 31, b = blk >> 11;
  const int hk = h >> 1;
  const int t0 = j * CHK;
  const int lane = tid & 63, wv = tid >> 6;
  const int fr = lane & 15, kg = lane >> 4;
  const int ty = tid >> 4, tx = tid & 15;

  const unsigned short* ksrc = kn + ((size_t)(b * 16 + hk) * T_ + t0) * 128;
  #pragma unroll
  for (int p = 0; p < 4; ++p) {
    int id = p * 256 + tid;
    int r = id >> 4, c = (id & 15) * 8;
    *(u16x8*)&kl[r][c] = *(const u16x8*)(ksrc + (size_t)r * 128 + c);
  }
  if (tid < 64) {
    float gval = gbuf[((size_t)b * HV_ + h) * T_ + t0 + tid];
    #pragma unroll
    for (int off = 1; off < 64; off <<= 1) {
      float o = __shfl_up(gval, off);
      if (tid >= off) gval += o;
    }
    gj[tid] = gval;
    gjc[((size_t)(b * HV_ + h) * NCH + j) * 64 + tid] = gval;
    bet[tid] = betab[((size_t)b * HV_ + h) * T_ + t0 + tid];
  }
  __syncthreads();

  // Gram via MFMA -> L strictly lower
  {
    const int s0 = 16 * wv;
    f32x4 ag[4];
    #pragma unroll
    for (int mt = 0; mt < 4; ++mt) ag[mt] = (f32x4){0.f, 0.f, 0.f, 0.f};
    #pragma unroll
    for (int ks = 0; ks < 4; ++ks) {
      short8 af = *(const short8*)&kl[s0 + fr][ks * 32 + kg * 8];
      #pragma unroll
      for (int mt = 0; mt < 4; ++mt) {
        short8 bfv = *(const short8*)&kl[mt * 16 + fr][ks * 32 + kg * 8];
        ag[mt] = __builtin_amdgcn_mfma_f32_16x16x32_bf16(af, bfv, ag[mt], 0, 0, 0);
      }
    }
    #pragma unroll
    for (int mt = 0; mt < 4; ++mt)
      #pragma unroll
      for (int e = 0; e < 4; ++e) {
        int l = s0 + kg * 4 + e, m = mt * 16 + fr;
        L[l][m] = (l > m) ? (-bet[l] * ag[mt][e] * expf(gj[l] - gj[m])) : 0.f;
      }
  }
  __syncthreads();
  for (int i = tid; i < CHK * CHK; i += 256) { int l = i >> 6, m = i & 63; W1[l][m] = L[l][m]; }
  __syncthreads();

  // doubling: L(=P) <- (I+L)(I+L^2)...(I+L^32) - I
  #pragma unroll
  for (int dk = 1; dk <= 5; ++dk) {
    const int p2 = 1 << (dk - 1);
    float s4[4][4];
    #pragma unroll
    for (int i = 0; i < 4; ++i)
      #pragma unroll
      for (int c = 0; c < 4; ++c) s4[i][c] = 0.f;
    {
      const int hi = 16 * wv + 15 - p2;
      for (int jm = p2; jm <= hi; ++jm) {
        float wl[4], wr[4];
        #pragma unroll
        for (int i = 0; i < 4; ++i) wl[i] = W1[ty * 4 + i][jm];
        #pragma unroll
        for (int c = 0; c < 4; ++c) wr[c] = W1[jm][tx * 4 + c];
        #pragma unroll
        for (int i = 0; i < 4; ++i)
          #pragma unroll
          for (int c = 0; c < 4; ++c) s4[i][c] += wl[i] * wr[c];
      }
    }
    __syncthreads();
    #pragma unroll
    for (int i = 0; i < 4; ++i)
      #pragma unroll
      for (int c = 0; c < 4; ++c) W1[ty * 4 + i][tx * 4 + c] = s4[i][c];
    __syncthreads();
    float pu[4][4];
    #pragma unroll
    for (int i = 0; i < 4; ++i)
      #pragma unroll
      for (int c = 0; c < 4; ++c) pu[i][c] = L[ty * 4 + i][tx * 4 + c] + W1[ty * 4 + i][tx * 4 + c];
    {
      const int hi = 16 * wv + 14;
      for (int jm = p2 * 2; jm <= hi; ++jm) {
        float pl[4], wr[4];
        #pragma unroll
        for (int i = 0; i < 4; ++i) pl[i] = L[ty * 4 + i][jm];
        #pragma unroll
        for (int c = 0; c < 4; ++c) wr[c] = W1[jm][tx * 4 + c];
        #pragma unroll
        for (int i = 0; i < 4; ++i)
          #pragma unroll
          for (int c = 0; c < 4; ++c) pu[i][c] += pl[i] * wr[c];
      }
    }
    __syncthreads();
    #pragma unroll
    for (int i = 0; i < 4; ++i)
      #pragma unroll
      for (int c = 0; c < 4; ++c) L[ty * 4 + i][tx * 4 + c] = pu[i][c];
    __syncthreads();
  }
  // store T = I + P (bf16)
  unsigned short* td = Tg + (size_t)blk * 4096;
  #pragma unroll
  for (int pp = 0; pp < 2; ++pp) {
    int id = pp * 256 + tid;
    int l = id >> 3, m8 = (id & 7) * 8;
    u16x8 o;
    #pragma unroll
    for (int e = 0; e < 8; ++e) {
      float v = L[l][m8 + e] + ((l == m8 + e) ? 1.f : 0.f);
      o[e] = f2bf(v);
    }
    *(u16x8*)(td + (size_t)l * 64 + m8) = o;
  }
}

// ---------------- scan: sequential over chunks, (b,h,u-slice) blocks ----------------
__global__ __launch_bounds__(256) void k_scan(const unsigned short* __restrict__ qn,
                                              const unsigned short* __restrict__ kn,
                                              const unsigned short* __restrict__ mv,
                                              const unsigned short* __restrict__ Tg,
                                              const float* __restrict__ gjc,
                                              const float* __restrict__ betab,
                                              const float* __restrict__ cw,
                                              unsigned short* __restrict__ xout) {
  __shared__ unsigned short kl[CHK][136], ql[CHK][136];
  __shared__ unsigned short Tl[CHK][72], intr[CHK][72];
  __shared__ float ST[16][132];            // S^T (u, a) f32
  __shared__ unsigned short SbT[16][136];  // bf16 S^T
  __shared__ unsigned short vbT[16][72], vnT[16][72], vndT[16][72];
  __shared__ float gj[CHK], bet[CHK], eg[CHK], edec[CHK], beg[CHK];

  const int tid = threadIdx.x;
  const int blk = blockIdx.x;
  const int us = blk & 7, h = (blk >> 3) & 31, b = blk >> 8;
  const int hk = h >> 1, u0 = us * 16;
  const int lane = tid & 63, wv = tid >> 6;
  const int fr = lane & 15, kg = lane >> 4;
  const int s0 = 16 * wv;

  // hoisted v-conv weights: thread handles (row cvl, channels c4..c4+3)
  const int cvl = tid >> 2, c4 = (tid & 3) * 4;
  float4 wv4[4];
  #pragma unroll
  for (int i = 0; i < 4; ++i)
    wv4[i] = *(const float4*)&cw[(size_t)(2 * KD_ + h * 128 + u0 + c4 + i) * 4];

  for (int i = tid; i < 16 * 132; i += 256) (&ST[0][0])[i] = 0.f;

  const unsigned short* qsrc = qn + (size_t)(b * 16 + hk) * T_ * 128;
  const unsigned short* ksrc = kn + (size_t)(b * 16 + hk) * T_ * 128;
  const unsigned short* tsrc = Tg + (size_t)((b * 32 + h) * 64) * 4096;
  const float* gsrc = gjc + (size_t)(b * 32 + h) * 4096;
  const float* bsrc = betab + ((size_t)b * HV_ + h) * T_;
  __syncthreads();

  for (int j = 0; j < NCH; ++j) {
    const int t0 = j * CHK;
    // stage k/q chunk (16KB each) + T (8KB)
    #pragma unroll
    for (int p = 0; p < 4; ++p) {
      int id = p * 256 + tid;
      int r = id >> 4, c = (id & 15) * 8;
      *(u16x8*)&kl[r][c] = *(const u16x8*)(ksrc + (size_t)(t0 + r) * 128 + c);
      *(u16x8*)&ql[r][c] = *(const u16x8*)(qsrc + (size_t)(t0 + r) * 128 + c);
    }
    #pragma unroll
    for (int p = 0; p < 2; ++p) {
      int id = p * 256 + tid;
      int r = id >> 3, c = (id & 7) * 8;
      *(u16x8*)&Tl[r][c] = *(const u16x8*)(tsrc + (size_t)j * 4096 + r * 64 + c);
    }
    if (tid < 64) {
      gj[tid] = gsrc[j * 64 + tid];
      bet[tid] = bsrc[t0 + tid];
    }
    __syncthreads();   // barrier1
    if (tid < 64) {
      float gl = gj[63];
      float e = expf(gj[tid]);
      eg[tid] = e;
      edec[tid] = expf(gl - gj[tid]);
      beg[tid] = bet[tid] * e;
    }
    // v conv + silu + beta -> vbT (transposed bf16)
    {
      float a4[4] = {0.f, 0.f, 0.f, 0.f};
      #pragma unroll
      for (int p = 0; p < 4; ++p) {
        int ts = t0 + cvl - 3 + p;
        if (ts >= 0) {
          u16x4 vv = *(const u16x4*)(mv + (size_t)(b * T_ + ts) * 4096 + h * 128 + u0 + c4);
          #pragma unroll
          for (int i = 0; i < 4; ++i) a4[i] += bf2f(vv[i]) * ((const float*)&wv4[i])[p];
        }
      }
      float be = bet[cvl];
      #pragma unroll
      for (int i = 0; i < 4; ++i) {
        float x = a4[i];
        x = x / (1.f + expf(-x)) * be;
        vbT[c4 + i][cvl] = f2bf(x);
      }
    }
    // SbT = bf16(S^T)
    {
      int u = tid >> 4, a8 = (tid & 15) * 8;
      u16x8 o;
      #pragma unroll
      for (int e = 0; e < 8; ++e) o[e] = f2bf(ST[u][a8 + e]);
      *(u16x8*)&SbT[u][a8] = o;
    }
    __syncthreads();   // barrier2: kl/ql/Tl/vbT/SbT/eg ready

    // Gram q@k^T -> intra (masked, decayed)
    {
      f32x4 ag[4];
      #pragma unroll
      for (int mt = 0; mt < 4; ++mt) ag[mt] = (f32x4){0.f, 0.f, 0.f, 0.f};
      #pragma unroll
      for (int ks = 0; ks < 4; ++ks) {
        short8 af = *(const short8*)&ql[s0 + fr][ks * 32 + kg * 8];
        #pragma unroll
        for (int mt = 0; mt < 4; ++mt) {
          short8 bfv = *(const short8*)&kl[mt * 16 + fr][ks * 32 + kg * 8];
          ag[mt] = __builtin_amdgcn_mfma_f32_16x16x32_bf16(af, bfv, ag[mt], 0, 0, 0);
        }
      }
      #pragma unroll
      for (int mt = 0; mt < 4; ++mt)
        #pragma unroll
        for (int e = 0; e < 4; ++e) {
          int l = s0 + kg * 4 + e, m = mt * 16 + fr;
          float v = (l >= m) ? (ag[mt][e] * expf(gj[l] - gj[m])) : 0.f;
          intr[l][m] = f2bf(v);
        }
    }
    // MM1: KS = k@S ; R = beg*KS ; vmr = vb - R (in place over vbT)
    {
      f32x4 a1 = (f32x4){0.f, 0.f, 0.f, 0.f};
      #pragma unroll
      for (int ks = 0; ks < 4; ++ks) {
        short8 af = *(const short8*)&kl[s0 + fr][ks * 32 + kg * 8];
        short8 bfv = *(const short8*)&SbT[fr][ks * 32 + kg * 8];
        a1 = __builtin_amdgcn_mfma_f32_16x16x32_bf16(af, bfv, a1, 0, 0, 0);
      }
      #pragma unroll
      for (int e = 0; e < 4; ++e) {
        int l = s0 + kg * 4 + e;
        float vm = bf2f(vbT[fr][l]) - beg[l] * a1[e];
        vbT[fr][l] = f2bf(vm);
      }
    }
    __syncthreads();   // barrier3: vmr, intra ready
    // MM2: v_new = T @ vmr
    {
      f32x4 a2 = (f32x4){0.f, 0.f, 0.f, 0.f};
      #pragma unroll
      for (int ks = 0; ks < 2; ++ks) {
        short8 af = *(const short8*)&Tl[s0 + fr][ks * 32 + kg * 8];
        short8 bfv = *(const short8*)&vbT[fr][ks * 32 + kg * 8];
        a2 = __builtin_amdgcn_mfma_f32_16x16x32_bf16(af, bfv, a2, 0, 0, 0);
      }
      #pragma unroll
      for (int e = 0; e < 4; ++e) {
        int l = s0 + kg * 4 + e;
        float vn = a2[e];
        vnT[fr][l] = f2bf(vn);
        vndT[fr][l] = f2bf(vn * edec[l]);
      }
    }
    __syncthreads();   // barrier4: vnT/vndT ready
    // MM4: intra@v_new ; MM5: q@S ; out
    {
      f32x4 ai = (f32x4){0.f, 0.f, 0.f, 0.f};
      f32x4 aq = (f32x4){0.f, 0.f, 0.f, 0.f};
      #pragma unroll
      for (int ks = 0; ks < 2; ++ks) {
        short8 af = *(const short8*)&intr[s0 + fr][ks * 32 + kg * 8];
        short8 bfv = *(const short8*)&vnT[fr][ks * 32 + kg * 8];
        ai = __builtin_amdgcn_mfma_f32_16x16x32_bf16(af, bfv, ai, 0, 0, 0);
      }
      #pragma unroll
      for (int ks = 0; ks < 4; ++ks) {
        short8 af = *(const short8*)&ql[s0 + fr][ks * 32 + kg * 8];
        short8 bfv = *(const short8*)&SbT[fr][ks * 32 + kg * 8];
        aq = __builtin_amdgcn_mfma_f32_16x16x32_bf16(af, bfv, aq, 0, 0, 0);
      }
      #pragma unroll
      for (int e = 0; e < 4; ++e) {
        int l = s0 + kg * 4 + e;
        float o = eg[l] * aq[e] + ai[e];
        xout[((size_t)(b * T_ + t0 + l) * HV_ + h) * UV_ + u0 + fr] = f2bf(o);
      }
    }
    // MM6 (VALU): S^T = aj*S^T + (edec*v_new)^T @ k
    {
      int u = tid >> 4, a8 = (tid & 15) * 8;
      float aj = eg[63];
      float s8[8];
      #pragma unroll
      for (int i = 0; i < 8; ++i) s8[i] = ST[u][a8 + i] * aj;
      for (int l = 0; l < CHK; ++l) {
        u16x8 kv = *(const u16x8*)&kl[l][a8];
        float vd = bf2f(vndT[u][l]);
        #pragma unroll
        for (int i = 0; i < 8; ++i) s8[i] += bf2f(kv[i]) * vd;
      }
      #pragma unroll
      for (int i = 0; i < 8; ++i) ST[u][a8 + i] = s8[i];
    }
    __syncthreads();   // end-of-chunk
  }
}

// ---------------- x * silu(z) -> RMSNorm -> bf16 ----------------
__global__ __launch_bounds__(256) void k_gate_norm(const unsigned short* __restrict__ x,
                                                   const unsigned short* __restrict__ z,
                                                   const float* __restrict__ nw,
                                                   unsigned short* __restrict__ out) {
  const int row = blockIdx.x * 4 + (threadIdx.x >> 6);
  const int lane = threadIdx.x & 63;
  const unsigned short* xp = x + (size_t)row * UV_;
  const unsigned short* zp = z + (size_t)row * UV_;
  float x0 = bf2f(xp[lane]), x1 = bf2f(xp[lane + 64]);
  float z0 = bf2f(zp[lane]), z1 = bf2f(zp[lane + 64]);
  float g0 = x0 * (z0 / (1.f + expf(-z0)));
  float g1 = x1 * (z1 / (1.f + expf(-z1)));
  float s = g0 * g0 + g1 * g1;
  #pragma unroll
  for (int off = 32; off > 0; off >>= 1) s += __shfl_xor(s, off);
  float r = rsqrtf(s * (1.f / UV_) + 1e-6f);
  out[(size_t)row * UV_ + lane]      = f2bf(nw[lane] * g0 * r);
  out[(size_t)row * UV_ + lane + 64] = f2bf(nw[lane + 64] * g1 * r);
}

// ---------------- launcher ----------------
extern "C" void kernel_launch(void* const* d_in, const int* in_sizes, int n_in,
                              void* d_out, int out_size, void* d_ws, size_t ws_size,
                              hipStream_t stream) {
  (void)in_sizes; (void)n_in; (void)out_size; (void)ws_size;
  const float* hidden  = (const float*)d_in[0];
  const float* W_qkv   = (const float*)d_in[1];
  const float* W_z     = (const float*)d_in[2];
  const float* W_b     = (const float*)d_in[3];
  const float* W_a     = (const float*)d_in[4];
  const float* conv_w  = (const float*)d_in[5];
  const float* dt_bias = (const float*)d_in[6];
  const float* A_log   = (const float*)d_in[7];
  const float* norm_w  = (const float*)d_in[8];
  const float* W_out   = (const float*)d_in[9];
  float* out = (float*)d_out;

  // workspace layout, 292 MiB peak (disjoint lifetimes):
  //  [  0, 32) wqkvT (->G1)          then Tg   (prep -> scan)
  //  [ 32, 96) mqk  (G1 -> k_qkv)    then xcore (scan -> gate_norm)
  //  [ 96,160) mv   (G1 -> scan)     then normed (gate_norm -> Gout)
  //  [160,224) qn   (k_qkv -> scan)  then zb
  //  [224,288) kn   (k_qkv -> scan)  then wzT [224,240) + woutT [240,256)
  //  [288,289) betab  [289,290) gbuf  [290,291) gjc
  const size_t MB = 1048576ull;
  char* w = (char*)d_ws;
  unsigned short* wqkvT = (unsigned short*)(w);
  unsigned short* Tg    = (unsigned short*)(w);
  unsigned short* mqk   = (unsigned short*)(w + 32 * MB);
  unsigned short* xcore = (unsigned short*)(w + 32 * MB);
  unsigned short* mv    = (unsigned short*)(w + 96 * MB);
  unsigned short* normed= (unsigned short*)(w + 96 * MB);
  unsigned short* qn    = (unsigned short*)(w + 160 * MB);
  unsigned short* zb    = (unsigned short*)(w + 160 * MB);
  unsigned short* kn    = (unsigned short*)(w + 224 * MB);
  unsigned short* wzT   = (unsigned short*)(w + 224 * MB);
  unsigned short* woutT = (unsigned short*)(w + 240 * MB);
  float*          betab = (float*)(w + 288 * MB);
  float*          gbuf  = (float*)(w + 289 * MB);
  float*          gjc   = (float*)(w + 290 * MB);

  // 1. W_qkv^T (CD,D)
  k_transpose<<<dim3(D_ / 32, CD_ / 32), dim3(32, 8), 0, stream>>>(W_qkv, wqkvT, D_, CD_);
  // 2. mqk = hidden @ W_qkv[:, :4096] ; mv = hidden @ W_qkv[:, 4096:]
  k_gemm<true, unsigned short><<<dim3(64, 32), 256, 0, stream>>>(hidden, wqkvT, mqk, 8192, 4096, 2048);
  k_gemm<true, unsigned short><<<dim3(64, 32), 256, 0, stream>>>(hidden, wqkvT + (size_t)4096 * 2048, mv, 8192, 4096, 2048);
  // 3. beta/g
  k_beta_g<<<dim3(B_ * T_ / 8), 256, 0, stream>>>(hidden, W_b, W_a, dt_bias, A_log, betab, gbuf);
  // 4. q/k conv+silu+l2norm
  k_qkv<<<dim3(B_ * T_), 256, 0, stream>>>(mqk, conv_w, qn, kn);
  // 5. prep: T matrices + gj cumsum
  k_prep<<<dim3(B_ * HV_ * NCH), 256, 0, stream>>>(kn, gbuf, betab, Tg, gjc);
  // 6. scan
  k_scan<<<dim3(B_ * HV_ * 8), 256, 0, stream>>>(qn, kn, mv, Tg, gjc, betab, conv_w, xcore);
  // 7. z path (into regions freed by scan)
  k_transpose<<<dim3(D_ / 32, VD_ / 32), dim3(32, 8), 0, stream>>>(W_z, wzT, D_, VD_);
  k_gemm<true, unsigned short><<<dim3(64, 32), 256, 0, stream>>>(hidden, wzT, zb, 8192, 4096, 2048);
  k_transpose<<<dim3(VD_ / 32, D_ / 32), dim3(32, 8), 0, stream>>>(W_out, woutT, VD_, D_);
  // 8. gate + RMSNorm
  k_gate_norm<<<dim3(B_ * T_ * HV_ / 4), 256, 0, stream>>>(xcore, zb, norm_w, normed);
  // 9. out = normed @ W_out
  k_gemm<false, float><<<dim3(64, 16), 256, 0, stream>>>(normed, woutT, out, 8192, 2048, 4096);
}

// Round 5
// 1997.507 us; speedup vs baseline: 3.6640x; 1.0770x over previous
//
#include <hip/hip_runtime.h>

// ---------------- problem constants ----------------
#define B_   2
#define T_   4096
#define D_   2048
#define HV_  32
#define AK_  128
#define UV_  128
#define KD_  2048          // KEY_DIM
#define VD_  4096          // VALUE_DIM
#define CD_  8192          // CONV_DIM
#define CHK  64            // chunk size
#define NCH  (T_/CHK)      // 64 chunks

typedef __attribute__((ext_vector_type(4))) float  f32x4;
typedef __attribute__((ext_vector_type(8))) short  short8;
typedef __attribute__((ext_vector_type(4))) short  short4b;
typedef __attribute__((ext_vector_type(8))) unsigned short u16x8;
typedef __attribute__((ext_vector_type(4))) unsigned short u16x4;

__device__ __forceinline__ float bf2f(unsigned short u) {
  return __uint_as_float(((unsigned)u) << 16);
}
__device__ __forceinline__ unsigned short f2bf(float f) { // RNE
  unsigned u = __float_as_uint(f);
  return (unsigned short)((u + 0x7fffu + ((u >> 16) & 1u)) >> 16);
}

// ---------------- transpose f32 (K,N) -> bf16 (N,K) ----------------
__global__ __launch_bounds__(256) void k_transpose(const float* __restrict__ src,
                                                   unsigned short* __restrict__ dst,
                                                   int K, int N) {
  __shared__ float tile[32][33];
  int k0 = blockIdx.x * 32, n0 = blockIdx.y * 32;
  int tx = threadIdx.x, ty = threadIdx.y;
  #pragma unroll
  for (int i = 0; i < 32; i += 8)
    tile[ty + i][tx] = src[(size_t)(k0 + ty + i) * N + n0 + tx];
  __syncthreads();
  #pragma unroll
  for (int i = 0; i < 32; i += 8)
    dst[(size_t)(n0 + ty + i) * K + k0 + tx] = f2bf(tile[tx][ty + i]);
}

// ---------------- MFMA GEMM (r3-proven): C(M,N) = A(M,K) * BT(N,K)^T ----------------
__device__ __forceinline__ void storeC(float* p, float v) { *p = v; }
__device__ __forceinline__ void storeC(unsigned short* p, float v) { *p = f2bf(v); }

template <bool AF32, typename CT>
__global__ __launch_bounds__(256) void k_gemm(const void* __restrict__ Av,
                                              const unsigned short* __restrict__ BT,
                                              CT* __restrict__ C, int M, int N, int K) {
  __shared__ short As[128 * 32];
  __shared__ short Bs[128 * 32];
  const int tid  = threadIdx.x;
  const size_t bm = (size_t)blockIdx.x * 128;
  const size_t bn = (size_t)blockIdx.y * 128;
  const int lane = tid & 63;
  const int wave = tid >> 6;
  const int wm = (wave >> 1) * 64;
  const int wn = (wave & 1) * 64;
  const int fr = lane & 15;
  const int kg = lane >> 4;
  const short* Bg = (const short*)BT + bn * K;

  f32x4 acc[4][4];
  #pragma unroll
  for (int i = 0; i < 4; ++i)
    #pragma unroll
    for (int j2 = 0; j2 < 4; ++j2) acc[i][j2] = (f32x4){0.f, 0.f, 0.f, 0.f};

  for (int kt = 0; kt < K; kt += 32) {
    __syncthreads();
    if constexpr (AF32) {
      const float* Ag = (const float*)Av + bm * (size_t)K;
      #pragma unroll
      for (int s = 0; s < 4; ++s) {
        int ch = s * 256 + tid;
        int r = ch >> 3, c4 = (ch & 7) * 4;
        float4 v = *(const float4*)(Ag + (size_t)r * K + kt + c4);
        short4b sv = { (short)f2bf(v.x), (short)f2bf(v.y), (short)f2bf(v.z), (short)f2bf(v.w) };
        *(short4b*)&As[r * 32 + c4] = sv;
      }
    } else {
      const short* Ag = (const short*)Av + bm * (size_t)K;
      #pragma unroll
      for (int s = 0; s < 2; ++s) {
        int ch = s * 256 + tid;
        int r = ch >> 2, kc8 = (ch & 3) * 8;
        *(short8*)&As[ch * 8] = *(const short8*)(Ag + (size_t)r * K + kt + kc8);
      }
    }
    #pragma unroll
    for (int s = 0; s < 2; ++s) {
      int ch = s * 256 + tid;
      int r = ch >> 2, kc8 = (ch & 3) * 8;
      *(short8*)&Bs[ch * 8] = *(const short8*)(Bg + (size_t)r * K + kt + kc8);
    }
    __syncthreads();
    short8 af[4], bfr[4];
    #pragma unroll
    for (int mi = 0; mi < 4; ++mi) af[mi]  = *(const short8*)&As[(wm + mi*16 + fr)*32 + kg*8];
    #pragma unroll
    for (int ni = 0; ni < 4; ++ni) bfr[ni] = *(const short8*)&Bs[(wn + ni*16 + fr)*32 + kg*8];
    #pragma unroll
    for (int mi = 0; mi < 4; ++mi)
      #pragma unroll
      for (int ni = 0; ni < 4; ++ni)
        acc[mi][ni] = __builtin_amdgcn_mfma_f32_16x16x32_bf16(af[mi], bfr[ni], acc[mi][ni], 0, 0, 0);
  }
  #pragma unroll
  for (int mi = 0; mi < 4; ++mi)
    #pragma unroll
    for (int ni = 0; ni < 4; ++ni) {
      size_t row = bm + wm + mi * 16 + kg * 4;
      size_t col = bn + wn + ni * 16 + fr;
      #pragma unroll
      for (int e = 0; e < 4; ++e) storeC(&C[(row + e) * (size_t)N + col], acc[mi][ni][e]);
    }
}

// ---------------- beta / g from hidden (f32, exact) ----------------
__global__ __launch_bounds__(256) void k_beta_g(const float* __restrict__ hidden,
                                                const float* __restrict__ Wb,
                                                const float* __restrict__ Wa,
                                                const float* __restrict__ dt_bias,
                                                const float* __restrict__ A_log,
                                                float* __restrict__ betab,
                                                float* __restrict__ gbuf) {
  const int tid = threadIdx.x;
  const int r = tid >> 5, hh = tid & 31;
  const size_t bt = (size_t)blockIdx.x * 8 + r;
  const float* hrow = hidden + bt * D_;
  float sb = 0.f, sa = 0.f;
  for (int d = 0; d < D_; ++d) {
    float hv = hrow[d];
    sb += hv * Wb[d * 32 + hh];
    sa += hv * Wa[d * 32 + hh];
  }
  float beta = 1.f / (1.f + expf(-sb));
  float xg = sa + dt_bias[hh];
  float sp = (xg > 20.f) ? xg : log1pf(expf(xg));
  float g = -expf(A_log[hh]) * sp;
  int b = (int)(bt >> 12);
  int t = (int)(bt & (T_ - 1));
  size_t o = ((size_t)b * HV_ + hh) * T_ + t;
  betab[o] = beta;
  gbuf[o] = g;
}

// ---------------- conv + silu + l2norm for q,k -> qn,kn (b,hk,t,128) bf16 ----------------
__global__ __launch_bounds__(256) void k_qkv(const unsigned short* __restrict__ mqk,
                                             const float* __restrict__ cw,
                                             unsigned short* __restrict__ qn,
                                             unsigned short* __restrict__ kn) {
  const int row = blockIdx.x;          // b*T + t
  const int b = row >> 12, t = row & (T_ - 1);
  const int tid = threadIdx.x;
  const int c0 = tid * 16;
  float4 w[16];
  #pragma unroll
  for (int e = 0; e < 16; ++e) w[e] = *(const float4*)&cw[(size_t)(c0 + e) * 4];
  float acc[16];
  #pragma unroll
  for (int e = 0; e < 16; ++e) acc[e] = 0.f;
  #pragma unroll
  for (int p = 0; p < 4; ++p) {
    int ts = t - 3 + p;
    if (ts < 0) continue;
    const unsigned short* src = mqk + (size_t)(b * T_ + ts) * 4096 + c0;
    u16x8 v0 = *(const u16x8*)src;
    u16x8 v1 = *(const u16x8*)(src + 8);
    #pragma unroll
    for (int e = 0; e < 8; ++e) {
      acc[e]     += bf2f(v0[e]) * ((const float*)&w[e])[p];
      acc[8 + e] += bf2f(v1[e]) * ((const float*)&w[8 + e])[p];
    }
  }
  float s = 0.f;
  #pragma unroll
  for (int e = 0; e < 16; ++e) {
    float x = acc[e];
    x = x / (1.f + expf(-x));
    acc[e] = x;
    s += x * x;
  }
  s += __shfl_xor(s, 1); s += __shfl_xor(s, 2); s += __shfl_xor(s, 4);
  float sc = rsqrtf(s + 1e-6f);
  bool isq = (c0 < KD_);
  if (isq) sc *= 0.08838834764831845f;   // * 128^-0.5 for q
  int ch = isq ? c0 : (c0 - KD_);
  int hk = ch >> 7, cc = ch & 127;
  unsigned short* dst = (isq ? qn : kn) + ((size_t)(b * 16 + hk) * T_ + t) * 128 + cc;
  u16x8 o0, o1;
  #pragma unroll
  for (int e = 0; e < 8; ++e) { o0[e] = f2bf(acc[e] * sc); o1[e] = f2bf(acc[8 + e] * sc); }
  *(u16x8*)dst = o0;
  *(u16x8*)(dst + 8) = o1;
}

// ---------------- prep: per (b,h,j) compute T = (I-L)^{-1} bf16 + gj cumsum ----------------
__global__ __launch_bounds__(256) void k_prep(const unsigned short* __restrict__ kn,
                                              const float* __restrict__ gbuf,
                                              const float* __restrict__ betab,
                                              unsigned short* __restrict__ Tg,
                                              float* __restrict__ gjc) {
  __shared__ __attribute__((aligned(16))) unsigned short kl[CHK][136];
  __shared__ float L[CHK][65];
  __shared__ float W1[CHK][65];
  __shared__ float gj[CHK], bet[CHK];
  const int tid = threadIdx.x;
  const int blk = blockIdx.x;
  const int j = blk & 63, h = (blk >> 6) & 31, b = blk >> 11;
  const int hk = h >> 1;
  const int t0 = j * CHK;
  const int lane = tid & 63, wv = tid >> 6;
  const int fr = lane & 15, kg = lane >> 4;
  const int ty = tid >> 4, tx = tid & 15;

  const unsigned short* ksrc = kn + ((size_t)(b * 16 + hk) * T_ + t0) * 128;
  #pragma unroll
  for (int p = 0; p < 4; ++p) {
    int id = p * 256 + tid;
    int r = id >> 4, c = (id & 15) * 8;
    *(u16x8*)&kl[r][c] = *(const u16x8*)(ksrc + (size_t)r * 128 + c);
  }
  if (tid < 64) {
    float gval = gbuf[((size_t)b * HV_ + h) * T_ + t0 + tid];
    #pragma unroll
    for (int off = 1; off < 64; off <<= 1) {
      float o = __shfl_up(gval, off);
      if (tid >= off) gval += o;
    }
    gj[tid] = gval;
    gjc[((size_t)(b * HV_ + h) * NCH + j) * 64 + tid] = gval;
    bet[tid] = betab[((size_t)b * HV_ + h) * T_ + t0 + tid];
  }
  __syncthreads();

  // Gram via MFMA -> L strictly lower
  {
    const int s0 = 16 * wv;
    f32x4 ag[4];
    #pragma unroll
    for (int mt = 0; mt < 4; ++mt) ag[mt] = (f32x4){0.f, 0.f, 0.f, 0.f};
    #pragma unroll
    for (int ks = 0; ks < 4; ++ks) {
      short8 af = *(const short8*)&kl[s0 + fr][ks * 32 + kg * 8];
      #pragma unroll
      for (int mt = 0; mt < 4; ++mt) {
        short8 bfv = *(const short8*)&kl[mt * 16 + fr][ks * 32 + kg * 8];
        ag[mt] = __builtin_amdgcn_mfma_f32_16x16x32_bf16(af, bfv, ag[mt], 0, 0, 0);
      }
    }
    #pragma unroll
    for (int mt = 0; mt < 4; ++mt)
      #pragma unroll
      for (int e = 0; e < 4; ++e) {
        int l = s0 + kg * 4 + e, m = mt * 16 + fr;
        L[l][m] = (l > m) ? (-bet[l] * ag[mt][e] * expf(gj[l] - gj[m])) : 0.f;
      }
  }
  __syncthreads();
  for (int i = tid; i < CHK * CHK; i += 256) { int l = i >> 6, m = i & 63; W1[l][m] = L[l][m]; }
  __syncthreads();

  // doubling: L(=P) <- (I+L)(I+L^2)...(I+L^32) - I
  #pragma unroll
  for (int dk = 1; dk <= 5; ++dk) {
    const int p2 = 1 << (dk - 1);
    float s4[4][4];
    #pragma unroll
    for (int i = 0; i < 4; ++i)
      #pragma unroll
      for (int c = 0; c < 4; ++c) s4[i][c] = 0.f;
    {
      const int hi = 16 * wv + 15 - p2;
      for (int jm = p2; jm <= hi; ++jm) {
        float wl[4], wr[4];
        #pragma unroll
        for (int i = 0; i < 4; ++i) wl[i] = W1[ty * 4 + i][jm];
        #pragma unroll
        for (int c = 0; c < 4; ++c) wr[c] = W1[jm][tx * 4 + c];
        #pragma unroll
        for (int i = 0; i < 4; ++i)
          #pragma unroll
          for (int c = 0; c < 4; ++c) s4[i][c] += wl[i] * wr[c];
      }
    }
    __syncthreads();
    #pragma unroll
    for (int i = 0; i < 4; ++i)
      #pragma unroll
      for (int c = 0; c < 4; ++c) W1[ty * 4 + i][tx * 4 + c] = s4[i][c];
    __syncthreads();
    float pu[4][4];
    #pragma unroll
    for (int i = 0; i < 4; ++i)
      #pragma unroll
      for (int c = 0; c < 4; ++c) pu[i][c] = L[ty * 4 + i][tx * 4 + c] + W1[ty * 4 + i][tx * 4 + c];
    {
      const int hi = 16 * wv + 14;
      for (int jm = p2 * 2; jm <= hi; ++jm) {
        float pl[4], wr[4];
        #pragma unroll
        for (int i = 0; i < 4; ++i) pl[i] = L[ty * 4 + i][jm];
        #pragma unroll
        for (int c = 0; c < 4; ++c) wr[c] = W1[jm][tx * 4 + c];
        #pragma unroll
        for (int i = 0; i < 4; ++i)
          #pragma unroll
          for (int c = 0; c < 4; ++c) pu[i][c] += pl[i] * wr[c];
      }
    }
    __syncthreads();
    #pragma unroll
    for (int i = 0; i < 4; ++i)
      #pragma unroll
      for (int c = 0; c < 4; ++c) L[ty * 4 + i][tx * 4 + c] = pu[i][c];
    __syncthreads();
  }
  // store T = I + P (bf16)
  unsigned short* td = Tg + (size_t)blk * 4096;
  #pragma unroll
  for (int pp = 0; pp < 2; ++pp) {
    int id = pp * 256 + tid;
    int l = id >> 3, m8 = (id & 7) * 8;
    u16x8 o;
    #pragma unroll
    for (int e = 0; e < 8; ++e) {
      float v = L[l][m8 + e] + ((l == m8 + e) ? 1.f : 0.f);
      o[e] = f2bf(v);
    }
    *(u16x8*)(td + (size_t)l * 64 + m8) = o;
  }
}

// ---------------- scan: sequential over chunks, (b,h,u-slice) blocks ----------------
__global__ __launch_bounds__(256) void k_scan(const unsigned short* __restrict__ qn,
                                              const unsigned short* __restrict__ kn,
                                              const unsigned short* __restrict__ mv,
                                              const unsigned short* __restrict__ Tg,
                                              const float* __restrict__ gjc,
                                              const float* __restrict__ betab,
                                              const float* __restrict__ cw,
                                              unsigned short* __restrict__ xout) {
  __shared__ __attribute__((aligned(16))) unsigned short kl[CHK][136], ql[CHK][136];
  __shared__ __attribute__((aligned(16))) unsigned short Ubuf[9216]; // Tl+intr OR kdT
  __shared__ float ST[16][132];            // S^T (u, a) f32
  __shared__ __attribute__((aligned(16))) unsigned short SbT[16][136];  // bf16 S^T
  __shared__ __attribute__((aligned(16))) unsigned short vbT[16][72], vnT[16][72];
  __shared__ float gj[CHK], bet[CHK], eg[CHK], edec[CHK], beg[CHK];

  unsigned short (*Tl)[72]   = (unsigned short(*)[72])(&Ubuf[0]);    // rows 0..63
  unsigned short (*intr)[72] = (unsigned short(*)[72])(&Ubuf[4608]); // rows 0..63
  unsigned short (*kdT)[72]  = (unsigned short(*)[72])(&Ubuf[0]);    // rows 0..127

  const int tid = threadIdx.x;
  const int blk = blockIdx.x;
  const int us = blk & 7, h = (blk >> 3) & 31, b = blk >> 8;
  const int hk = h >> 1, u0 = us * 16;
  const int lane = tid & 63, wv = tid >> 6;
  const int fr = lane & 15, kg = lane >> 4;
  const int s0 = 16 * wv;

  // hoisted v-conv weights: thread handles (row cvl, channels c4..c4+3)
  const int cvl = tid >> 2, c4 = (tid & 3) * 4;
  float4 wv4[4];
  #pragma unroll
  for (int i = 0; i < 4; ++i)
    wv4[i] = *(const float4*)&cw[(size_t)(2 * KD_ + h * 128 + u0 + c4 + i) * 4];

  for (int i = tid; i < 16 * 132; i += 256) (&ST[0][0])[i] = 0.f;

  const unsigned short* qsrc = qn + (size_t)(b * 16 + hk) * T_ * 128;
  const unsigned short* ksrc = kn + (size_t)(b * 16 + hk) * T_ * 128;
  const unsigned short* tsrc = Tg + (size_t)((b * 32 + h) * 64) * 4096;
  const float* gsrc = gjc + (size_t)(b * 32 + h) * 4096;
  const float* bsrc = betab + ((size_t)b * HV_ + h) * T_;
  __syncthreads();

  for (int j = 0; j < NCH; ++j) {
    const int t0 = j * CHK;
    // stage k/q chunk (16KB each) + T (8KB into U)
    #pragma unroll
    for (int p = 0; p < 4; ++p) {
      int id = p * 256 + tid;
      int r = id >> 4, c = (id & 15) * 8;
      *(u16x8*)&kl[r][c] = *(const u16x8*)(ksrc + (size_t)(t0 + r) * 128 + c);
      *(u16x8*)&ql[r][c] = *(const u16x8*)(qsrc + (size_t)(t0 + r) * 128 + c);
    }
    #pragma unroll
    for (int p = 0; p < 2; ++p) {
      int id = p * 256 + tid;
      int r = id >> 3, c = (id & 7) * 8;
      *(u16x8*)&Tl[r][c] = *(const u16x8*)(tsrc + (size_t)j * 4096 + r * 64 + c);
    }
    if (tid < 64) {
      gj[tid] = gsrc[j * 64 + tid];
      bet[tid] = bsrc[t0 + tid];
    }
    __syncthreads();   // barrier1
    if (tid < 64) {
      float gl = gj[63];
      float e = expf(gj[tid]);
      eg[tid] = e;
      edec[tid] = expf(gl - gj[tid]);
      beg[tid] = bet[tid] * e;
    }
    // v conv + silu + beta -> vbT (transposed bf16)
    {
      float a4[4] = {0.f, 0.f, 0.f, 0.f};
      #pragma unroll
      for (int p = 0; p < 4; ++p) {
        int ts = t0 + cvl - 3 + p;
        if (ts >= 0) {
          u16x4 vv = *(const u16x4*)(mv + (size_t)(b * T_ + ts) * 4096 + h * 128 + u0 + c4);
          #pragma unroll
          for (int i = 0; i < 4; ++i) a4[i] += bf2f(vv[i]) * ((const float*)&wv4[i])[p];
        }
      }
      float be = bet[cvl];
      #pragma unroll
      for (int i = 0; i < 4; ++i) {
        float x = a4[i];
        x = x / (1.f + expf(-x)) * be;
        vbT[c4 + i][cvl] = f2bf(x);
      }
    }
    // SbT = bf16(S^T)
    {
      int u = tid >> 4, a8 = (tid & 15) * 8;
      u16x8 o;
      #pragma unroll
      for (int e = 0; e < 8; ++e) o[e] = f2bf(ST[u][a8 + e]);
      *(u16x8*)&SbT[u][a8] = o;
    }
    __syncthreads();   // barrier2: kl/ql/Tl/vbT/SbT/eg/edec ready

    // Gram q@k^T -> intra (masked, decayed)
    {
      f32x4 ag[4];
      #pragma unroll
      for (int mt = 0; mt < 4; ++mt) ag[mt] = (f32x4){0.f, 0.f, 0.f, 0.f};
      #pragma unroll
      for (int ks = 0; ks < 4; ++ks) {
        short8 af = *(const short8*)&ql[s0 + fr][ks * 32 + kg * 8];
        #pragma unroll
        for (int mt = 0; mt < 4; ++mt) {
          short8 bfv = *(const short8*)&kl[mt * 16 + fr][ks * 32 + kg * 8];
          ag[mt] = __builtin_amdgcn_mfma_f32_16x16x32_bf16(af, bfv, ag[mt], 0, 0, 0);
        }
      }
      #pragma unroll
      for (int mt = 0; mt < 4; ++mt)
        #pragma unroll
        for (int e = 0; e < 4; ++e) {
          int l = s0 + kg * 4 + e, m = mt * 16 + fr;
          float v = (l >= m) ? (ag[mt][e] * expf(gj[l] - gj[m])) : 0.f;
          intr[l][m] = f2bf(v);
        }
    }
    // MM1: KS = k@S ; vmr = vb - beg*KS (in place over vbT)
    {
      f32x4 a1 = (f32x4){0.f, 0.f, 0.f, 0.f};
      #pragma unroll
      for (int ks = 0; ks < 4; ++ks) {
        short8 af = *(const short8*)&kl[s0 + fr][ks * 32 + kg * 8];
        short8 bfv = *(const short8*)&SbT[fr][ks * 32 + kg * 8];
        a1 = __builtin_amdgcn_mfma_f32_16x16x32_bf16(af, bfv, a1, 0, 0, 0);
      }
      #pragma unroll
      for (int e = 0; e < 4; ++e) {
        int l = s0 + kg * 4 + e;
        float vm = bf2f(vbT[fr][l]) - beg[l] * a1[e];
        vbT[fr][l] = f2bf(vm);
      }
    }
    __syncthreads();   // barrier3: vmr, intra ready
    // MM2: v_new = T @ vmr
    {
      f32x4 a2 = (f32x4){0.f, 0.f, 0.f, 0.f};
      #pragma unroll
      for (int ks = 0; ks < 2; ++ks) {
        short8 af = *(const short8*)&Tl[s0 + fr][ks * 32 + kg * 8];
        short8 bfv = *(const short8*)&vbT[fr][ks * 32 + kg * 8];
        a2 = __builtin_amdgcn_mfma_f32_16x16x32_bf16(af, bfv, a2, 0, 0, 0);
      }
      #pragma unroll
      for (int e = 0; e < 4; ++e) {
        int l = s0 + kg * 4 + e;
        vnT[fr][l] = f2bf(a2[e]);
      }
    }
    __syncthreads();   // barrier4: vnT ready
    // MM4: intra@v_new ; MM5: q@S ; out
    {
      f32x4 ai = (f32x4){0.f, 0.f, 0.f, 0.f};
      f32x4 aq = (f32x4){0.f, 0.f, 0.f, 0.f};
      #pragma unroll
      for (int ks = 0; ks < 2; ++ks) {
        short8 af = *(const short8*)&intr[s0 + fr][ks * 32 + kg * 8];
        short8 bfv = *(const short8*)&vnT[fr][ks * 32 + kg * 8];
        ai = __builtin_amdgcn_mfma_f32_16x16x32_bf16(af, bfv, ai, 0, 0, 0);
      }
      #pragma unroll
      for (int ks = 0; ks < 4; ++ks) {
        short8 af = *(const short8*)&ql[s0 + fr][ks * 32 + kg * 8];
        short8 bfv = *(const short8*)&SbT[fr][ks * 32 + kg * 8];
        aq = __builtin_amdgcn_mfma_f32_16x16x32_bf16(af, bfv, aq, 0, 0, 0);
      }
      #pragma unroll
      for (int e = 0; e < 4; ++e) {
        int l = s0 + kg * 4 + e;
        float o = eg[l] * aq[e] + ai[e];
        xout[((size_t)(b * T_ + t0 + l) * HV_ + h) * UV_ + u0 + fr] = f2bf(o);
      }
    }
    __syncthreads();   // barrier5: intra/Tl reads done -> Ubuf reusable
    // build kdT[a][l] = k[l][a] * edec[l]  (overlays Tl+intr)
    #pragma unroll
    for (int p = 0; p < 2; ++p) {
      int id = p * 256 + tid;
      int l = id & 63, a16 = (id >> 6) * 16;
      u16x8 k0 = *(const u16x8*)&kl[l][a16];
      u16x8 k1 = *(const u16x8*)&kl[l][a16 + 8];
      float ed = edec[l];
      #pragma unroll
      for (int e = 0; e < 8; ++e) {
        kdT[a16 + e][l]     = f2bf(bf2f(k0[e]) * ed);
        kdT[a16 + 8 + e][l] = f2bf(bf2f(k1[e]) * ed);
      }
    }
    __syncthreads();   // barrier6: kdT ready
    // MM6 (MFMA): S^T = eg[63]*S^T + v_new^T(edec) @ k   [D(u,a) = vn(u,l) x kd(a,l)]
    {
      float egl = eg[63];
      #pragma unroll
      for (int t2 = 0; t2 < 2; ++t2) {
        int a0 = wv * 32 + t2 * 16;
        f32x4 cf;
        #pragma unroll
        for (int e = 0; e < 4; ++e) cf[e] = ST[kg * 4 + e][a0 + fr] * egl;
        #pragma unroll
        for (int ks = 0; ks < 2; ++ks) {
          short8 af  = *(const short8*)&vnT[fr][ks * 32 + kg * 8];
          short8 bfv = *(const short8*)&kdT[a0 + fr][ks * 32 + kg * 8];
          cf = __builtin_amdgcn_mfma_f32_16x16x32_bf16(af, bfv, cf, 0, 0, 0);
        }
        #pragma unroll
        for (int e = 0; e < 4; ++e) ST[kg * 4 + e][a0 + fr] = cf[e];
      }
    }
    __syncthreads();   // end-of-chunk: ST updated before next SbT/Tl staging
  }
}

// ---------------- x * silu(z) -> RMSNorm -> bf16 ----------------
__global__ __launch_bounds__(256) void k_gate_norm(const unsigned short* __restrict__ x,
                                                   const unsigned short* __restrict__ z,
                                                   const float* __restrict__ nw,
                                                   unsigned short* __restrict__ out) {
  const int row = blockIdx.x * 4 + (threadIdx.x >> 6);
  const int lane = threadIdx.x & 63;
  const unsigned short* xp = x + (size_t)row * UV_;
  const unsigned short* zp = z + (size_t)row * UV_;
  float x0 = bf2f(xp[lane]), x1 = bf2f(xp[lane + 64]);
  float z0 = bf2f(zp[lane]), z1 = bf2f(zp[lane + 64]);
  float g0 = x0 * (z0 / (1.f + expf(-z0)));
  float g1 = x1 * (z1 / (1.f + expf(-z1)));
  float s = g0 * g0 + g1 * g1;
  #pragma unroll
  for (int off = 32; off > 0; off >>= 1) s += __shfl_xor(s, off);
  float r = rsqrtf(s * (1.f / UV_) + 1e-6f);
  out[(size_t)row * UV_ + lane]      = f2bf(nw[lane] * g0 * r);
  out[(size_t)row * UV_ + lane + 64] = f2bf(nw[lane + 64] * g1 * r);
}

// ---------------- launcher ----------------
extern "C" void kernel_launch(void* const* d_in, const int* in_sizes, int n_in,
                              void* d_out, int out_size, void* d_ws, size_t ws_size,
                              hipStream_t stream) {
  (void)in_sizes; (void)n_in; (void)out_size; (void)ws_size;
  const float* hidden  = (const float*)d_in[0];
  const float* W_qkv   = (const float*)d_in[1];
  const float* W_z     = (const float*)d_in[2];
  const float* W_b     = (const float*)d_in[3];
  const float* W_a     = (const float*)d_in[4];
  const float* conv_w  = (const float*)d_in[5];
  const float* dt_bias = (const float*)d_in[6];
  const float* A_log   = (const float*)d_in[7];
  const float* norm_w  = (const float*)d_in[8];
  const float* W_out   = (const float*)d_in[9];
  float* out = (float*)d_out;

  // workspace layout, 291 MiB peak (identical to round-3 proven layout):
  //  [  0, 32) wqkvT (->G1)          then Tg   (prep -> scan)
  //  [ 32, 96) mqk  (G1 -> k_qkv)    then xcore (scan -> gate_norm)
  //  [ 96,160) mv   (G1 -> scan)     then normed (gate_norm -> Gout)
  //  [160,224) qn   (k_qkv -> scan)  then zb
  //  [224,288) kn   (k_qkv -> scan)  then wzT [224,240) + woutT [240,256)
  //  [288,289) betab  [289,290) gbuf  [290,291) gjc
  const size_t MB = 1048576ull;
  char* w = (char*)d_ws;
  unsigned short* wqkvT = (unsigned short*)(w);
  unsigned short* Tg    = (unsigned short*)(w);
  unsigned short* mqk   = (unsigned short*)(w + 32 * MB);
  unsigned short* xcore = (unsigned short*)(w + 32 * MB);
  unsigned short* mv    = (unsigned short*)(w + 96 * MB);
  unsigned short* normed= (unsigned short*)(w + 96 * MB);
  unsigned short* qn    = (unsigned short*)(w + 160 * MB);
  unsigned short* zb    = (unsigned short*)(w + 160 * MB);
  unsigned short* kn    = (unsigned short*)(w + 224 * MB);
  unsigned short* wzT   = (unsigned short*)(w + 224 * MB);
  unsigned short* woutT = (unsigned short*)(w + 240 * MB);
  float*          betab = (float*)(w + 288 * MB);
  float*          gbuf  = (float*)(w + 289 * MB);
  float*          gjc   = (float*)(w + 290 * MB);

  // 1. W_qkv^T (CD,D)
  k_transpose<<<dim3(D_ / 32, CD_ / 32), dim3(32, 8), 0, stream>>>(W_qkv, wqkvT, D_, CD_);
  // 2. mqk = hidden @ W_qkv[:, :4096] ; mv = hidden @ W_qkv[:, 4096:]
  k_gemm<true, unsigned short><<<dim3(64, 32), 256, 0, stream>>>(hidden, wqkvT, mqk, 8192, 4096, 2048);
  k_gemm<true, unsigned short><<<dim3(64, 32), 256, 0, stream>>>(hidden, wqkvT + (size_t)4096 * 2048, mv, 8192, 4096, 2048);
  // 3. beta/g
  k_beta_g<<<dim3(B_ * T_ / 8), 256, 0, stream>>>(hidden, W_b, W_a, dt_bias, A_log, betab, gbuf);
  // 4. q/k conv+silu+l2norm
  k_qkv<<<dim3(B_ * T_), 256, 0, stream>>>(mqk, conv_w, qn, kn);
  // 5. prep: T matrices + gj cumsum
  k_prep<<<dim3(B_ * HV_ * NCH), 256, 0, stream>>>(kn, gbuf, betab, Tg, gjc);
  // 6. scan
  k_scan<<<dim3(B_ * HV_ * 8), 256, 0, stream>>>(qn, kn, mv, Tg, gjc, betab, conv_w, xcore);
  // 7. z path (into regions freed by scan)
  k_transpose<<<dim3(D_ / 32, VD_ / 32), dim3(32, 8), 0, stream>>>(W_z, wzT, D_, VD_);
  k_gemm<true, unsigned short><<<dim3(64, 32), 256, 0, stream>>>(hidden, wzT, zb, 8192, 4096, 2048);
  k_transpose<<<dim3(VD_ / 32, D_ / 32), dim3(32, 8), 0, stream>>>(W_out, woutT, VD_, D_);
  // 8. gate + RMSNorm
  k_gate_norm<<<dim3(B_ * T_ * HV_ / 4), 256, 0, stream>>>(xcore, zb, norm_w, normed);
  // 9. out = normed @ W_out
  k_gemm<false, float><<<dim3(64, 16), 256, 0, stream>>>(normed, woutT, out, 8192, 2048, 4096);
}

// Round 6
// 1996.719 us; speedup vs baseline: 3.6654x; 1.0004x over previous
//
#include <hip/hip_runtime.h>

// ---------------- problem constants ----------------
#define B_   2
#define T_   4096
#define D_   2048
#define HV_  32
#define AK_  128
#define UV_  128
#define KD_  2048          // KEY_DIM
#define VD_  4096          // VALUE_DIM
#define CD_  8192          // CONV_DIM
#define CHK  64            // chunk size
#define NCH  (T_/CHK)      // 64 chunks

typedef __attribute__((ext_vector_type(4))) float  f32x4;
typedef __attribute__((ext_vector_type(8))) short  short8;
typedef __attribute__((ext_vector_type(4))) short  short4b;
typedef __attribute__((ext_vector_type(8))) unsigned short u16x8;
typedef __attribute__((ext_vector_type(4))) unsigned short u16x4;

__device__ __forceinline__ float bf2f(unsigned short u) {
  return __uint_as_float(((unsigned)u) << 16);
}
__device__ __forceinline__ unsigned short f2bf(float f) { // RNE
  unsigned u = __float_as_uint(f);
  return (unsigned short)((u + 0x7fffu + ((u >> 16) & 1u)) >> 16);
}
__device__ __forceinline__ void gload16(const void* g, void* l) {
  __builtin_amdgcn_global_load_lds((const __attribute__((address_space(1))) void*)g,
                                   (__attribute__((address_space(3))) void*)l, 16, 0, 0);
}

// ---------------- transpose f32 (K,N) -> bf16 (N,K) ----------------
__global__ __launch_bounds__(256) void k_transpose(const float* __restrict__ src,
                                                   unsigned short* __restrict__ dst,
                                                   int K, int N) {
  __shared__ float tile[32][33];
  int k0 = blockIdx.x * 32, n0 = blockIdx.y * 32;
  int tx = threadIdx.x, ty = threadIdx.y;
  #pragma unroll
  for (int i = 0; i < 32; i += 8)
    tile[ty + i][tx] = src[(size_t)(k0 + ty + i) * N + n0 + tx];
  __syncthreads();
  #pragma unroll
  for (int i = 0; i < 32; i += 8)
    dst[(size_t)(n0 + ty + i) * K + k0 + tx] = f2bf(tile[tx][ty + i]);
}

// ---------------- MFMA GEMM: C(M,N) = A(M,K) * BT(N,K)^T ----------------
// B always staged via global_load_lds (width 16).
// A: AGL=true -> bf16 A via global_load_lds ; AGL=false -> f32 A via reg-convert staging.
__device__ __forceinline__ void storeC(float* p, float v) { *p = v; }
__device__ __forceinline__ void storeC(unsigned short* p, float v) { *p = f2bf(v); }

template <bool AGL, typename CT>
__global__ __launch_bounds__(256) void k_gemm(const void* __restrict__ Av,
                                              const unsigned short* __restrict__ BT,
                                              CT* __restrict__ C, int M, int N, int K) {
  __shared__ __attribute__((aligned(16))) short As[128 * 32];
  __shared__ __attribute__((aligned(16))) short Bs[128 * 32];
  const int tid  = threadIdx.x;
  const size_t bm = (size_t)blockIdx.x * 128;
  const size_t bn = (size_t)blockIdx.y * 128;
  const int lane = tid & 63;
  const int wave = tid >> 6;
  const int wm = (wave >> 1) * 64;
  const int wn = (wave & 1) * 64;
  const int fr = lane & 15;
  const int kg = lane >> 4;
  // gload lane mapping: lane L -> row L>>2 (of 16-row group), col (L&3)*8 shorts.
  // HW writes lane L's 16B at ldsbase + L*16, which equals (L>>2)*64 + (L&3)*16 bytes. [verified]
  const int lr = lane >> 2, lc8 = (lane & 3) * 8;
  const short* gb = (const short*)BT + (bn + wave * 32 + lr) * (size_t)K + lc8;
  short* lB = &Bs[wave * 32 * 32];
  const short* gab = (const short*)Av + (bm + wave * 32 + lr) * (size_t)K + lc8; // AGL path
  short* lA = &As[wave * 32 * 32];

  f32x4 acc[4][4];
  #pragma unroll
  for (int i = 0; i < 4; ++i)
    #pragma unroll
    for (int j2 = 0; j2 < 4; ++j2) acc[i][j2] = (f32x4){0.f, 0.f, 0.f, 0.f};

  for (int kt = 0; kt < K; kt += 32) {
    __syncthreads();
    // issue B DMA first (latency hides under A staging / VALU)
    gload16(gb + kt, lB);
    gload16(gb + kt + (size_t)16 * K, lB + 16 * 32);
    if constexpr (AGL) {
      gload16(gab + kt, lA);
      gload16(gab + kt + (size_t)16 * K, lA + 16 * 32);
    } else {
      const float* Ag = (const float*)Av + bm * (size_t)K;
      #pragma unroll
      for (int s = 0; s < 4; ++s) {           // 1024 float4-chunks (128x32 f32)
        int ch = s * 256 + tid;
        int r = ch >> 3, c4 = (ch & 7) * 4;
        float4 v = *(const float4*)(Ag + (size_t)r * K + kt + c4);
        short4b sv = { (short)f2bf(v.x), (short)f2bf(v.y), (short)f2bf(v.z), (short)f2bf(v.w) };
        *(short4b*)&As[r * 32 + c4] = sv;
      }
    }
    __syncthreads();
    short8 af[4], bfr[4];
    #pragma unroll
    for (int mi = 0; mi < 4; ++mi) af[mi]  = *(const short8*)&As[(wm + mi*16 + fr)*32 + kg*8];
    #pragma unroll
    for (int ni = 0; ni < 4; ++ni) bfr[ni] = *(const short8*)&Bs[(wn + ni*16 + fr)*32 + kg*8];
    #pragma unroll
    for (int mi = 0; mi < 4; ++mi)
      #pragma unroll
      for (int ni = 0; ni < 4; ++ni)
        acc[mi][ni] = __builtin_amdgcn_mfma_f32_16x16x32_bf16(af[mi], bfr[ni], acc[mi][ni], 0, 0, 0);
  }
  #pragma unroll
  for (int mi = 0; mi < 4; ++mi)
    #pragma unroll
    for (int ni = 0; ni < 4; ++ni) {
      size_t row = bm + wm + mi * 16 + kg * 4;
      size_t col = bn + wn + ni * 16 + fr;
      #pragma unroll
      for (int e = 0; e < 4; ++e) storeC(&C[(row + e) * (size_t)N + col], acc[mi][ni][e]);
    }
}

// ---------------- beta / g from hidden (f32, exact) ----------------
__global__ __launch_bounds__(256) void k_beta_g(const float* __restrict__ hidden,
                                                const float* __restrict__ Wb,
                                                const float* __restrict__ Wa,
                                                const float* __restrict__ dt_bias,
                                                const float* __restrict__ A_log,
                                                float* __restrict__ betab,
                                                float* __restrict__ gbuf) {
  const int tid = threadIdx.x;
  const int r = tid >> 5, hh = tid & 31;
  const size_t bt = (size_t)blockIdx.x * 8 + r;
  const float* hrow = hidden + bt * D_;
  float sb = 0.f, sa = 0.f;
  for (int d = 0; d < D_; ++d) {
    float hv = hrow[d];
    sb += hv * Wb[d * 32 + hh];
    sa += hv * Wa[d * 32 + hh];
  }
  float beta = 1.f / (1.f + expf(-sb));
  float xg = sa + dt_bias[hh];
  float sp = (xg > 20.f) ? xg : log1pf(expf(xg));
  float g = -expf(A_log[hh]) * sp;
  int b = (int)(bt >> 12);
  int t = (int)(bt & (T_ - 1));
  size_t o = ((size_t)b * HV_ + hh) * T_ + t;
  betab[o] = beta;
  gbuf[o] = g;
}

// ---------------- conv + silu + l2norm for q,k -> qn,kn (b,hk,t,128) bf16 ----------------
__global__ __launch_bounds__(256) void k_qkv(const unsigned short* __restrict__ mqk,
                                             const float* __restrict__ cw,
                                             unsigned short* __restrict__ qn,
                                             unsigned short* __restrict__ kn) {
  const int row = blockIdx.x;          // b*T + t
  const int b = row >> 12, t = row & (T_ - 1);
  const int tid = threadIdx.x;
  const int c0 = tid * 16;
  float4 w[16];
  #pragma unroll
  for (int e = 0; e < 16; ++e) w[e] = *(const float4*)&cw[(size_t)(c0 + e) * 4];
  float acc[16];
  #pragma unroll
  for (int e = 0; e < 16; ++e) acc[e] = 0.f;
  #pragma unroll
  for (int p = 0; p < 4; ++p) {
    int ts = t - 3 + p;
    if (ts < 0) continue;
    const unsigned short* src = mqk + (size_t)(b * T_ + ts) * 4096 + c0;
    u16x8 v0 = *(const u16x8*)src;
    u16x8 v1 = *(const u16x8*)(src + 8);
    #pragma unroll
    for (int e = 0; e < 8; ++e) {
      acc[e]     += bf2f(v0[e]) * ((const float*)&w[e])[p];
      acc[8 + e] += bf2f(v1[e]) * ((const float*)&w[8 + e])[p];
    }
  }
  float s = 0.f;
  #pragma unroll
  for (int e = 0; e < 16; ++e) {
    float x = acc[e];
    x = x / (1.f + expf(-x));
    acc[e] = x;
    s += x * x;
  }
  s += __shfl_xor(s, 1); s += __shfl_xor(s, 2); s += __shfl_xor(s, 4);
  float sc = rsqrtf(s + 1e-6f);
  bool isq = (c0 < KD_);
  if (isq) sc *= 0.08838834764831845f;   // * 128^-0.5 for q
  int ch = isq ? c0 : (c0 - KD_);
  int hk = ch >> 7, cc = ch & 127;
  unsigned short* dst = (isq ? qn : kn) + ((size_t)(b * 16 + hk) * T_ + t) * 128 + cc;
  u16x8 o0, o1;
  #pragma unroll
  for (int e = 0; e < 8; ++e) { o0[e] = f2bf(acc[e] * sc); o1[e] = f2bf(acc[8 + e] * sc); }
  *(u16x8*)dst = o0;
  *(u16x8*)(dst + 8) = o1;
}

// ---------------- prep: per (b,h,j) compute T = (I-L)^{-1} bf16 + gj cumsum ----------------
__global__ __launch_bounds__(256) void k_prep(const unsigned short* __restrict__ kn,
                                              const float* __restrict__ gbuf,
                                              const float* __restrict__ betab,
                                              unsigned short* __restrict__ Tg,
                                              float* __restrict__ gjc) {
  __shared__ __attribute__((aligned(16))) unsigned short kl[CHK][136];
  __shared__ float L[CHK][65];
  __shared__ float W1[CHK][65];
  __shared__ float gj[CHK], bet[CHK];
  const int tid = threadIdx.x;
  const int blk = blockIdx.x;
  const int j = blk & 63, h = (blk >> 6) & 31, b = blk >> 11;
  const int hk = h >> 1;
  const int t0 = j * CHK;
  const int lane = tid & 63, wv = tid >> 6;
  const int fr = lane & 15, kg = lane >> 4;
  const int ty = tid >> 4, tx = tid & 15;

  const unsigned short* ksrc = kn + ((size_t)(b * 16 + hk) * T_ + t0) * 128;
  #pragma unroll
  for (int p = 0; p < 4; ++p) {
    int id = p * 256 + tid;
    int r = id >> 4, c = (id & 15) * 8;
    *(u16x8*)&kl[r][c] = *(const u16x8*)(ksrc + (size_t)r * 128 + c);
  }
  if (tid < 64) {
    float gval = gbuf[((size_t)b * HV_ + h) * T_ + t0 + tid];
    #pragma unroll
    for (int off = 1; off < 64; off <<= 1) {
      float o = __shfl_up(gval, off);
      if (tid >= off) gval += o;
    }
    gj[tid] = gval;
    gjc[((size_t)(b * HV_ + h) * NCH + j) * 64 + tid] = gval;
    bet[tid] = betab[((size_t)b * HV_ + h) * T_ + t0 + tid];
  }
  __syncthreads();

  // Gram via MFMA -> L strictly lower
  {
    const int s0 = 16 * wv;
    f32x4 ag[4];
    #pragma unroll
    for (int mt = 0; mt < 4; ++mt) ag[mt] = (f32x4){0.f, 0.f, 0.f, 0.f};
    #pragma unroll
    for (int ks = 0; ks < 4; ++ks) {
      short8 af = *(const short8*)&kl[s0 + fr][ks * 32 + kg * 8];
      #pragma unroll
      for (int mt = 0; mt < 4; ++mt) {
        short8 bfv = *(const short8*)&kl[mt * 16 + fr][ks * 32 + kg * 8];
        ag[mt] = __builtin_amdgcn_mfma_f32_16x16x32_bf16(af, bfv, ag[mt], 0, 0, 0);
      }
    }
    #pragma unroll
    for (int mt = 0; mt < 4; ++mt)
      #pragma unroll
      for (int e = 0; e < 4; ++e) {
        int l = s0 + kg * 4 + e, m = mt * 16 + fr;
        L[l][m] = (l > m) ? (-bet[l] * ag[mt][e] * expf(gj[l] - gj[m])) : 0.f;
      }
  }
  __syncthreads();
  for (int i = tid; i < CHK * CHK; i += 256) { int l = i >> 6, m = i & 63; W1[l][m] = L[l][m]; }
  __syncthreads();

  // doubling: L(=P) <- (I+L)(I+L^2)...(I+L^32) - I
  #pragma unroll
  for (int dk = 1; dk <= 5; ++dk) {
    const int p2 = 1 << (dk - 1);
    float s4[4][4];
    #pragma unroll
    for (int i = 0; i < 4; ++i)
      #pragma unroll
      for (int c = 0; c < 4; ++c) s4[i][c] = 0.f;
    {
      const int hi = 16 * wv + 15 - p2;
      for (int jm = p2; jm <= hi; ++jm) {
        float wl[4], wr[4];
        #pragma unroll
        for (int i = 0; i < 4; ++i) wl[i] = W1[ty * 4 + i][jm];
        #pragma unroll
        for (int c = 0; c < 4; ++c) wr[c] = W1[jm][tx * 4 + c];
        #pragma unroll
        for (int i = 0; i < 4; ++i)
          #pragma unroll
          for (int c = 0; c < 4; ++c) s4[i][c] += wl[i] * wr[c];
      }
    }
    __syncthreads();
    #pragma unroll
    for (int i = 0; i < 4; ++i)
      #pragma unroll
      for (int c = 0; c < 4; ++c) W1[ty * 4 + i][tx * 4 + c] = s4[i][c];
    __syncthreads();
    float pu[4][4];
    #pragma unroll
    for (int i = 0; i < 4; ++i)
      #pragma unroll
      for (int c = 0; c < 4; ++c) pu[i][c] = L[ty * 4 + i][tx * 4 + c] + W1[ty * 4 + i][tx * 4 + c];
    {
      const int hi = 16 * wv + 14;
      for (int jm = p2 * 2; jm <= hi; ++jm) {
        float pl[4], wr[4];
        #pragma unroll
        for (int i = 0; i < 4; ++i) pl[i] = L[ty * 4 + i][jm];
        #pragma unroll
        for (int c = 0; c < 4; ++c) wr[c] = W1[jm][tx * 4 + c];
        #pragma unroll
        for (int i = 0; i < 4; ++i)
          #pragma unroll
          for (int c = 0; c < 4; ++c) pu[i][c] += pl[i] * wr[c];
      }
    }
    __syncthreads();
    #pragma unroll
    for (int i = 0; i < 4; ++i)
      #pragma unroll
      for (int c = 0; c < 4; ++c) L[ty * 4 + i][tx * 4 + c] = pu[i][c];
    __syncthreads();
  }
  // store T = I + P (bf16)
  unsigned short* td = Tg + (size_t)blk * 4096;
  #pragma unroll
  for (int pp = 0; pp < 2; ++pp) {
    int id = pp * 256 + tid;
    int l = id >> 3, m8 = (id & 7) * 8;
    u16x8 o;
    #pragma unroll
    for (int e = 0; e < 8; ++e) {
      float v = L[l][m8 + e] + ((l == m8 + e) ? 1.f : 0.f);
      o[e] = f2bf(v);
    }
    *(u16x8*)(td + (size_t)l * 64 + m8) = o;
  }
}

// ---------------- scan: sequential over chunks, (b,h,u-slice) blocks ----------------
__global__ __launch_bounds__(256) void k_scan(const unsigned short* __restrict__ qn,
                                              const unsigned short* __restrict__ kn,
                                              const unsigned short* __restrict__ mv,
                                              const unsigned short* __restrict__ Tg,
                                              const float* __restrict__ gjc,
                                              const float* __restrict__ betab,
                                              const float* __restrict__ cw,
                                              unsigned short* __restrict__ xout) {
  __shared__ __attribute__((aligned(16))) unsigned short kl[CHK][136], ql[CHK][136];
  __shared__ __attribute__((aligned(16))) unsigned short Ubuf[9216]; // Tl+intr OR kdT
  __shared__ float ST[16][132];            // S^T (u, a) f32
  __shared__ __attribute__((aligned(16))) unsigned short SbT[16][136];  // bf16 S^T
  __shared__ __attribute__((aligned(16))) unsigned short vbT[16][72], vnT[16][72];
  __shared__ float gj[CHK], bet[CHK], eg[CHK], edec[CHK], beg[CHK];

  unsigned short (*Tl)[72]   = (unsigned short(*)[72])(&Ubuf[0]);    // rows 0..63
  unsigned short (*intr)[72] = (unsigned short(*)[72])(&Ubuf[4608]); // rows 0..63
  unsigned short (*kdT)[72]  = (unsigned short(*)[72])(&Ubuf[0]);    // rows 0..127

  const int tid = threadIdx.x;
  const int blk = blockIdx.x;
  const int us = blk & 7, h = (blk >> 3) & 31, b = blk >> 8;
  const int hk = h >> 1, u0 = us * 16;
  const int lane = tid & 63, wv = tid >> 6;
  const int fr = lane & 15, kg = lane >> 4;
  const int s0 = 16 * wv;

  // hoisted v-conv weights: thread handles (row cvl, channels c4..c4+3)
  const int cvl = tid >> 2, c4 = (tid & 3) * 4;
  float4 wv4[4];
  #pragma unroll
  for (int i = 0; i < 4; ++i)
    wv4[i] = *(const float4*)&cw[(size_t)(2 * KD_ + h * 128 + u0 + c4 + i) * 4];

  for (int i = tid; i < 16 * 132; i += 256) (&ST[0][0])[i] = 0.f;

  const unsigned short* qsrc = qn + (size_t)(b * 16 + hk) * T_ * 128;
  const unsigned short* ksrc = kn + (size_t)(b * 16 + hk) * T_ * 128;
  const unsigned short* tsrc = Tg + (size_t)((b * 32 + h) * 64) * 4096;
  const float* gsrc = gjc + (size_t)(b * 32 + h) * 4096;
  const float* bsrc = betab + ((size_t)b * HV_ + h) * T_;
  __syncthreads();

  for (int j = 0; j < NCH; ++j) {
    const int t0 = j * CHK;
    // stage k/q chunk (16KB each) + T (8KB into U)
    #pragma unroll
    for (int p = 0; p < 4; ++p) {
      int id = p * 256 + tid;
      int r = id >> 4, c = (id & 15) * 8;
      *(u16x8*)&kl[r][c] = *(const u16x8*)(ksrc + (size_t)(t0 + r) * 128 + c);
      *(u16x8*)&ql[r][c] = *(const u16x8*)(qsrc + (size_t)(t0 + r) * 128 + c);
    }
    #pragma unroll
    for (int p = 0; p < 2; ++p) {
      int id = p * 256 + tid;
      int r = id >> 3, c = (id & 7) * 8;
      *(u16x8*)&Tl[r][c] = *(const u16x8*)(tsrc + (size_t)j * 4096 + r * 64 + c);
    }
    if (tid < 64) {
      gj[tid] = gsrc[j * 64 + tid];
      bet[tid] = bsrc[t0 + tid];
    }
    __syncthreads();   // barrier1
    if (tid < 64) {
      float gl = gj[63];
      float e = expf(gj[tid]);
      eg[tid] = e;
      edec[tid] = expf(gl - gj[tid]);
      beg[tid] = bet[tid] * e;
    }
    // v conv + silu + beta -> vbT (transposed bf16)
    {
      float a4[4] = {0.f, 0.f, 0.f, 0.f};
      #pragma unroll
      for (int p = 0; p < 4; ++p) {
        int ts = t0 + cvl - 3 + p;
        if (ts >= 0) {
          u16x4 vv = *(const u16x4*)(mv + (size_t)(b * T_ + ts) * 4096 + h * 128 + u0 + c4);
          #pragma unroll
          for (int i = 0; i < 4; ++i) a4[i] += bf2f(vv[i]) * ((const float*)&wv4[i])[p];
        }
      }
      float be = bet[cvl];
      #pragma unroll
      for (int i = 0; i < 4; ++i) {
        float x = a4[i];
        x = x / (1.f + expf(-x)) * be;
        vbT[c4 + i][cvl] = f2bf(x);
      }
    }
    // SbT = bf16(S^T)
    {
      int u = tid >> 4, a8 = (tid & 15) * 8;
      u16x8 o;
      #pragma unroll
      for (int e = 0; e < 8; ++e) o[e] = f2bf(ST[u][a8 + e]);
      *(u16x8*)&SbT[u][a8] = o;
    }
    __syncthreads();   // barrier2: kl/ql/Tl/vbT/SbT/eg/edec ready

    // Gram q@k^T -> intra (masked, decayed)
    {
      f32x4 ag[4];
      #pragma unroll
      for (int mt = 0; mt < 4; ++mt) ag[mt] = (f32x4){0.f, 0.f, 0.f, 0.f};
      #pragma unroll
      for (int ks = 0; ks < 4; ++ks) {
        short8 af = *(const short8*)&ql[s0 + fr][ks * 32 + kg * 8];
        #pragma unroll
        for (int mt = 0; mt < 4; ++mt) {
          short8 bfv = *(const short8*)&kl[mt * 16 + fr][ks * 32 + kg * 8];
          ag[mt] = __builtin_amdgcn_mfma_f32_16x16x32_bf16(af, bfv, ag[mt], 0, 0, 0);
        }
      }
      #pragma unroll
      for (int mt = 0; mt < 4; ++mt)
        #pragma unroll
        for (int e = 0; e < 4; ++e) {
          int l = s0 + kg * 4 + e, m = mt * 16 + fr;
          float v = (l >= m) ? (ag[mt][e] * expf(gj[l] - gj[m])) : 0.f;
          intr[l][m] = f2bf(v);
        }
    }
    // MM1: KS = k@S ; vmr = vb - beg*KS (in place over vbT)
    {
      f32x4 a1 = (f32x4){0.f, 0.f, 0.f, 0.f};
      #pragma unroll
      for (int ks = 0; ks < 4; ++ks) {
        short8 af = *(const short8*)&kl[s0 + fr][ks * 32 + kg * 8];
        short8 bfv = *(const short8*)&SbT[fr][ks * 32 + kg * 8];
        a1 = __builtin_amdgcn_mfma_f32_16x16x32_bf16(af, bfv, a1, 0, 0, 0);
      }
      #pragma unroll
      for (int e = 0; e < 4; ++e) {
        int l = s0 + kg * 4 + e;
        float vm = bf2f(vbT[fr][l]) - beg[l] * a1[e];
        vbT[fr][l] = f2bf(vm);
      }
    }
    __syncthreads();   // barrier3: vmr, intra ready
    // MM2: v_new = T @ vmr
    {
      f32x4 a2 = (f32x4){0.f, 0.f, 0.f, 0.f};
      #pragma unroll
      for (int ks = 0; ks < 2; ++ks) {
        short8 af = *(const short8*)&Tl[s0 + fr][ks * 32 + kg * 8];
        short8 bfv = *(const short8*)&vbT[fr][ks * 32 + kg * 8];
        a2 = __builtin_amdgcn_mfma_f32_16x16x32_bf16(af, bfv, a2, 0, 0, 0);
      }
      #pragma unroll
      for (int e = 0; e < 4; ++e) {
        int l = s0 + kg * 4 + e;
        vnT[fr][l] = f2bf(a2[e]);
      }
    }
    __syncthreads();   // barrier4: vnT ready
    // MM4: intra@v_new ; MM5: q@S ; out
    {
      f32x4 ai = (f32x4){0.f, 0.f, 0.f, 0.f};
      f32x4 aq = (f32x4){0.f, 0.f, 0.f, 0.f};
      #pragma unroll
      for (int ks = 0; ks < 2; ++ks) {
        short8 af = *(const short8*)&intr[s0 + fr][ks * 32 + kg * 8];
        short8 bfv = *(const short8*)&vnT[fr][ks * 32 + kg * 8];
        ai = __builtin_amdgcn_mfma_f32_16x16x32_bf16(af, bfv, ai, 0, 0, 0);
      }
      #pragma unroll
      for (int ks = 0; ks < 4; ++ks) {
        short8 af = *(const short8*)&ql[s0 + fr][ks * 32 + kg * 8];
        short8 bfv = *(const short8*)&SbT[fr][ks * 32 + kg * 8];
        aq = __builtin_amdgcn_mfma_f32_16x16x32_bf16(af, bfv, aq, 0, 0, 0);
      }
      #pragma unroll
      for (int e = 0; e < 4; ++e) {
        int l = s0 + kg * 4 + e;
        float o = eg[l] * aq[e] + ai[e];
        xout[((size_t)(b * T_ + t0 + l) * HV_ + h) * UV_ + u0 + fr] = f2bf(o);
      }
    }
    __syncthreads();   // barrier5: intra/Tl reads done -> Ubuf reusable
    // build kdT[a][l] = k[l][a] * edec[l]  (overlays Tl+intr)
    #pragma unroll
    for (int p = 0; p < 2; ++p) {
      int id = p * 256 + tid;
      int l = id & 63, a16 = (id >> 6) * 16;
      u16x8 k0 = *(const u16x8*)&kl[l][a16];
      u16x8 k1 = *(const u16x8*)&kl[l][a16 + 8];
      float ed = edec[l];
      #pragma unroll
      for (int e = 0; e < 8; ++e) {
        kdT[a16 + e][l]     = f2bf(bf2f(k0[e]) * ed);
        kdT[a16 + 8 + e][l] = f2bf(bf2f(k1[e]) * ed);
      }
    }
    __syncthreads();   // barrier6: kdT ready
    // MM6 (MFMA): S^T = eg[63]*S^T + v_new^T(edec) @ k   [D(u,a) = vn(u,l) x kd(a,l)]
    {
      float egl = eg[63];
      #pragma unroll
      for (int t2 = 0; t2 < 2; ++t2) {
        int a0 = wv * 32 + t2 * 16;
        f32x4 cf;
        #pragma unroll
        for (int e = 0; e < 4; ++e) cf[e] = ST[kg * 4 + e][a0 + fr] * egl;
        #pragma unroll
        for (int ks = 0; ks < 2; ++ks) {
          short8 af  = *(const short8*)&vnT[fr][ks * 32 + kg * 8];
          short8 bfv = *(const short8*)&kdT[a0 + fr][ks * 32 + kg * 8];
          cf = __builtin_amdgcn_mfma_f32_16x16x32_bf16(af, bfv, cf, 0, 0, 0);
        }
        #pragma unroll
        for (int e = 0; e < 4; ++e) ST[kg * 4 + e][a0 + fr] = cf[e];
      }
    }
    __syncthreads();   // end-of-chunk: ST updated before next SbT/Tl staging
  }
}

// ---------------- x * silu(z) -> RMSNorm -> bf16 ----------------
__global__ __launch_bounds__(256) void k_gate_norm(const unsigned short* __restrict__ x,
                                                   const unsigned short* __restrict__ z,
                                                   const float* __restrict__ nw,
                                                   unsigned short* __restrict__ out) {
  const int row = blockIdx.x * 4 + (threadIdx.x >> 6);
  const int lane = threadIdx.x & 63;
  const unsigned short* xp = x + (size_t)row * UV_;
  const unsigned short* zp = z + (size_t)row * UV_;
  float x0 = bf2f(xp[lane]), x1 = bf2f(xp[lane + 64]);
  float z0 = bf2f(zp[lane]), z1 = bf2f(zp[lane + 64]);
  float g0 = x0 * (z0 / (1.f + expf(-z0)));
  float g1 = x1 * (z1 / (1.f + expf(-z1)));
  float s = g0 * g0 + g1 * g1;
  #pragma unroll
  for (int off = 32; off > 0; off >>= 1) s += __shfl_xor(s, off);
  float r = rsqrtf(s * (1.f / UV_) + 1e-6f);
  out[(size_t)row * UV_ + lane]      = f2bf(nw[lane] * g0 * r);
  out[(size_t)row * UV_ + lane + 64] = f2bf(nw[lane + 64] * g1 * r);
}

// ---------------- launcher ----------------
extern "C" void kernel_launch(void* const* d_in, const int* in_sizes, int n_in,
                              void* d_out, int out_size, void* d_ws, size_t ws_size,
                              hipStream_t stream) {
  (void)in_sizes; (void)n_in; (void)out_size; (void)ws_size;
  const float* hidden  = (const float*)d_in[0];
  const float* W_qkv   = (const float*)d_in[1];
  const float* W_z     = (const float*)d_in[2];
  const float* W_b     = (const float*)d_in[3];
  const float* W_a     = (const float*)d_in[4];
  const float* conv_w  = (const float*)d_in[5];
  const float* dt_bias = (const float*)d_in[6];
  const float* A_log   = (const float*)d_in[7];
  const float* norm_w  = (const float*)d_in[8];
  const float* W_out   = (const float*)d_in[9];
  float* out = (float*)d_out;

  // workspace layout, 291 MiB peak (identical to round-3/5 proven layout):
  //  [  0, 32) wqkvT (->G1)          then Tg   (prep -> scan)
  //  [ 32, 96) mqk  (G1 -> k_qkv)    then xcore (scan -> gate_norm)
  //  [ 96,160) mv   (G1 -> scan)     then normed (gate_norm -> Gout)
  //  [160,224) qn   (k_qkv -> scan)  then zb
  //  [224,288) kn   (k_qkv -> scan)  then wzT [224,240) + woutT [240,256)
  //  [288,289) betab  [289,290) gbuf  [290,291) gjc
  const size_t MB = 1048576ull;
  char* w = (char*)d_ws;
  unsigned short* wqkvT = (unsigned short*)(w);
  unsigned short* Tg    = (unsigned short*)(w);
  unsigned short* mqk   = (unsigned short*)(w + 32 * MB);
  unsigned short* xcore = (unsigned short*)(w + 32 * MB);
  unsigned short* mv    = (unsigned short*)(w + 96 * MB);
  unsigned short* normed= (unsigned short*)(w + 96 * MB);
  unsigned short* qn    = (unsigned short*)(w + 160 * MB);
  unsigned short* zb    = (unsigned short*)(w + 160 * MB);
  unsigned short* kn    = (unsigned short*)(w + 224 * MB);
  unsigned short* wzT   = (unsigned short*)(w + 224 * MB);
  unsigned short* woutT = (unsigned short*)(w + 240 * MB);
  float*          betab = (float*)(w + 288 * MB);
  float*          gbuf  = (float*)(w + 289 * MB);
  float*          gjc   = (float*)(w + 290 * MB);

  // 1. W_qkv^T (CD,D)
  k_transpose<<<dim3(D_ / 32, CD_ / 32), dim3(32, 8), 0, stream>>>(W_qkv, wqkvT, D_, CD_);
  // 2. mqk = hidden @ W_qkv[:, :4096] ; mv = hidden @ W_qkv[:, 4096:]
  k_gemm<false, unsigned short><<<dim3(64, 32), 256, 0, stream>>>(hidden, wqkvT, mqk, 8192, 4096, 2048);
  k_gemm<false, unsigned short><<<dim3(64, 32), 256, 0, stream>>>(hidden, wqkvT + (size_t)4096 * 2048, mv, 8192, 4096, 2048);
  // 3. beta/g
  k_beta_g<<<dim3(B_ * T_ / 8), 256, 0, stream>>>(hidden, W_b, W_a, dt_bias, A_log, betab, gbuf);
  // 4. q/k conv+silu+l2norm
  k_qkv<<<dim3(B_ * T_), 256, 0, stream>>>(mqk, conv_w, qn, kn);
  // 5. prep: T matrices + gj cumsum
  k_prep<<<dim3(B_ * HV_ * NCH), 256, 0, stream>>>(kn, gbuf, betab, Tg, gjc);
  // 6. scan
  k_scan<<<dim3(B_ * HV_ * 8), 256, 0, stream>>>(qn, kn, mv, Tg, gjc, betab, conv_w, xcore);
  // 7. z path (into regions freed by scan)
  k_transpose<<<dim3(D_ / 32, VD_ / 32), dim3(32, 8), 0, stream>>>(W_z, wzT, D_, VD_);
  k_gemm<false, unsigned short><<<dim3(64, 32), 256, 0, stream>>>(hidden, wzT, zb, 8192, 4096, 2048);
  k_transpose<<<dim3(VD_ / 32, D_ / 32), dim3(32, 8), 0, stream>>>(W_out, woutT, VD_, D_);
  // 8. gate + RMSNorm
  k_gate_norm<<<dim3(B_ * T_ * HV_ / 4), 256, 0, stream>>>(xcore, zb, norm_w, normed);
  // 9. out = normed @ W_out  (A bf16 -> full gload)
  k_gemm<true, float><<<dim3(64, 16), 256, 0, stream>>>(normed, woutT, out, 8192, 2048, 4096);
}